// Round 18
// baseline (323.085 us; speedup 1.0000x reference)
//
#include <hip/hip_runtime.h>

typedef __bf16 bf16;
typedef __attribute__((ext_vector_type(2))) __bf16 bf16x2;
typedef __attribute__((ext_vector_type(4))) __bf16 bf16x4;
typedef __attribute__((ext_vector_type(8))) __bf16 bf16x8;
typedef __attribute__((ext_vector_type(4))) float f32x4;

// ---------------- workspace layout (bytes) ----------------
constexpr size_t OFF_CATSEQ = 0;          // 16777216  [b][p][c(0:512 vi,512:1024 ir)] bf16
constexpr size_t OFF_WBF    = 16777216;   // 2097152   Wq,Wk,Wv,Wo bf16 [co][c]
constexpr size_t OFF_ENHW   = 18874368;   // 4718592   enh_w repacked [t][co][ci] bf16
constexpr size_t OFF_GW1R   = 23592960;   // 589824    gate_w1 repacked [t][hid][ci] bf16
constexpr size_t OFF_CHS    = 24182784;   // 4096      bn scale[512], shift[512]
constexpr size_t OFF_ZP     = 24186880;   // 256       zero page
constexpr size_t OFF_POOL   = 24187136;   // 16384     enh split-K counters (256 int)
constexpr size_t OFF_HID    = 24203520;   // 65536
constexpr size_t OFF_KW     = 24269056;   // 1024
constexpr size_t OFF_Q      = 24270080;   // 8388608  [b][h][p][d] bf16 (x0.125*log2e); later: enh partials (2x16.78MB f32)
constexpr size_t OFF_K      = 32658688;   // 8388608  [b][h][p][d] bf16
constexpr size_t OFF_VT     = 41047296;   // 8388608  [b][h][d][p] bf16; reused as enh partial kg=1
constexpr size_t OFF_CTX    = 49435904;   // 8388608  [b][p][c] bf16
constexpr size_t OFF_FF     = 57824512;   // 8388608  fused_feat [b][c][p] bf16
constexpr size_t OFF_G1P    = 66213120;   // 9437184  gate1 partials [t][b][32][1024] f32 (early: mlp2 logits)
constexpr size_t OFF_Y1     = 75650304;   // 1048576  y1 [b][32][1024] f32 (early: pool partials [b*8+pt][1024])
constexpr size_t OFF_GSUM   = 76698880;   // 32768    [b][p] f32
constexpr size_t OFF_F2     = 76731648;   // 8388608  fused2 [b][p][c] bf16
// total 85120256 bytes

struct KParams {
  const float *vi, *ir, *bq, *bk, *bv, *bo, *gb1;
  char* ws;
  float* out;
};

__device__ __forceinline__ void gload16(const void* g, void* l) {
  __builtin_amdgcn_global_load_lds(
      (const __attribute__((address_space(1))) unsigned int*)g,
      (__attribute__((address_space(3))) unsigned int*)l, 16, 0, 0);
}

template<int N> __device__ __forceinline__ void waitvm() {
  if constexpr (N==0) asm volatile("s_waitcnt vmcnt(0)" ::: "memory");
  else if constexpr (N==1) asm volatile("s_waitcnt vmcnt(1)" ::: "memory");
  else if constexpr (N==2) asm volatile("s_waitcnt vmcnt(2)" ::: "memory");
  else if constexpr (N==3) asm volatile("s_waitcnt vmcnt(3)" ::: "memory");
  else if constexpr (N==4) asm volatile("s_waitcnt vmcnt(4)" ::: "memory");
  else if constexpr (N==6) asm volatile("s_waitcnt vmcnt(6)" ::: "memory");
  else if constexpr (N==8) asm volatile("s_waitcnt vmcnt(8)" ::: "memory");
  else asm volatile("s_waitcnt vmcnt(12)" ::: "memory");
}

// ---------------- merged prep: QKVO cast, bn-fold, zero page, counters, enh/gw1 repack, cat+pool ----------------
// blocks [0,4100): scalar range; [4100,4612): enh repack; [4612,4644): gw1 repack; [4644,6692): cat
__global__ __launch_bounds__(256) void k_prep(const float* vi, const float* ir,
                        const float* Wq, const float* Wk, const float* Wv, const float* Wo,
                        const float* enh_w, const float* gw1,
                        const float* enh_b, const float* gamma, const float* beta,
                        const float* mean, const float* var,
                        bf16* wbf, bf16* enhw, bf16* gw1r, float* chs, float* zp,
                        int* cnt, bf16* cat, float* pool)
{
  __shared__ float ld[9216];
  int blk = blockIdx.x, tid = threadIdx.x;
  if (blk < 4100) {
    long i = (long)blk*256 + tid;
    if (i < 1048576) {
      int which = (int)(i >> 18); long r = i & 262143;
      const float* s = which==0?Wq: which==1?Wk: which==2?Wv:Wo;
      wbf[i] = (bf16)s[r];
    } else if (i < 1048576+512) {
      int c = (int)(i - 1048576);
      float sc = gamma[c]*rsqrtf(var[c]+1e-5f);
      chs[c] = sc; chs[512+c] = (enh_b[c]-mean[c])*sc + beta[c];
    } else if (i < 1048576+512+64) {
      zp[i - (1048576+512)] = 0.f;
    } else if (i < 1048576+512+64+256) {
      cnt[i - (1048576+512+64)] = 0;
    }
  } else if (blk < 4100+512) {
    int co = blk - 4100;
    const float* src = enh_w + (long)co*4608;     // [ci][3][3] contiguous
    #pragma unroll
    for (int it=0; it<18; ++it) ld[tid + 256*it] = src[tid + 256*it];
    __syncthreads();
    #pragma unroll
    for (int t=0;t<9;++t) {
      int ci = tid*2;
      bf16x2 v = { (bf16)ld[ci*9 + t], (bf16)ld[(ci+1)*9 + t] };
      ((bf16x2*)(enhw + (long)t*262144 + (long)co*512))[tid] = v;
    }
  } else if (blk < 4100+512+32) {
    int hid = blk - (4100+512);
    const float* src = gw1 + (long)hid*9216;      // [ci=1024][3][3]
    #pragma unroll
    for (int it=0; it<36; ++it) ld[tid + 256*it] = src[tid + 256*it];
    __syncthreads();
    #pragma unroll
    for (int t=0;t<9;++t) {
      int ci = tid*4;
      bf16x4 v = { (bf16)ld[ci*9+t], (bf16)ld[(ci+1)*9+t],
                   (bf16)ld[(ci+2)*9+t], (bf16)ld[(ci+3)*9+t] };
      *(bf16x4*)(gw1r + (long)t*32768 + (long)hid*1024 + ci) = v;
    }
  } else {
    int idx = blk - (4100+512+32);
    int pt = idx&7, ct = (idx>>3)&31, b = idx>>8;
    const float* src = (ct < 16) ? vi : ir;
    int c0 = (ct & 15) * 32;
    int p0 = pt * 128;
    for (int it = 0; it < 4; ++it) {
      int row = it*8 + (tid>>5);
      int pc  = (tid & 31) * 4;
      float4 v = *(const float4*)(src + ((long)(b*512 + c0 + row))*1024 + p0 + pc);
      ld[row*129+pc+0]=v.x; ld[row*129+pc+1]=v.y; ld[row*129+pc+2]=v.z; ld[row*129+pc+3]=v.w;
    }
    __syncthreads();
    int p = tid >> 1, half = tid & 1;
    bf16x8 o0, o1;
    #pragma unroll
    for (int j = 0; j < 8; ++j) o0[j] = (bf16)ld[(half*16 + j)*129 + p];
    #pragma unroll
    for (int j = 0; j < 8; ++j) o1[j] = (bf16)ld[(half*16 + 8 + j)*129 + p];
    long ccol = (ct<16 ? 0 : 512) + c0 + half*16;
    bf16* dst = cat + ((long)(b*1024 + p0 + p))*1024 + ccol;
    *(bf16x8*)dst       = o0;
    *((bf16x8*)dst + 1) = o1;
    // fused pool partial
    {
      int c = tid>>3, j = tid&7;
      float s = 0.f;
      #pragma unroll
      for (int i=0;i<16;++i) s += ld[c*129 + j*16+i];
      s += __shfl_down(s, 4);
      s += __shfl_down(s, 2);
      s += __shfl_down(s, 1);
      if (j==0) {
        int pc_ = (ct<16 ? 0 : 512) + c0 + c;
        pool[((long)(b*8+pt))*1024 + pc_] = s;
      }
    }
  }
}

// ---------------- mlp1: wave-per-row, partial-sum staging (partials [b*8+pt][1024], vi+ir halves) ----------------
__global__ __launch_bounds__(256) void k_mlp1(const float* partial, const float* w1, const float* b1, float* hid)
{
  __shared__ float pl[8*512];
  int tid = threadIdx.x;
  const float4* pp4 = (const float4*)partial;   // [b*8+pt][256 float4]
  #pragma unroll
  for (int k=0;k<4;++k) {
    int j = tid + 256*k;          // b*128 + c4
    int b = j>>7, c4 = j&127;
    float4 s = {0,0,0,0};
    #pragma unroll
    for (int pt=0;pt<8;++pt) {
      float4 v = pp4[(b*8+pt)*256 + c4];
      float4 w = pp4[(b*8+pt)*256 + 128 + c4];
      s.x+=v.x+w.x; s.y+=v.y+w.y; s.z+=v.z+w.z; s.w+=v.w+w.w;
    }
    float4 o = {s.x*(1.f/1024.f), s.y*(1.f/1024.f), s.z*(1.f/1024.f), s.w*(1.f/1024.f)};
    ((float4*)pl)[j] = o;
  }
  __syncthreads();
  int lane = tid&63, wave = tid>>6;
  #pragma unroll
  for (int rr=0; rr<4; ++rr) {
    int row = (blockIdx.x*4 + wave)*4 + rr;
    const float* wr = w1 + (long)row*512;
    float acc[8] = {};
    #pragma unroll
    for (int e=0;e<8;++e) {
      int c = lane + 64*e;
      float w = wr[c];
      #pragma unroll
      for (int b=0;b<8;++b) acc[b] += w * pl[b*512+c];
    }
    #pragma unroll
    for (int b=0;b<8;++b) {
      float s = acc[b];
      #pragma unroll
      for (int off=32; off; off>>=1) s += __shfl_down(s, off);
      if (lane==0) hid[b*2048 + row] = fmaxf(s + b1[row], 0.f);
    }
  }
}

// ---------------- mlp2a: one block per (b,j) logit ----------------
__global__ __launch_bounds__(256) void k_mlp2a(const float* hid, const float* w2, const float* b2, float* lg)
{
  int blk = blockIdx.x; int b = blk/25, j = blk%25;
  int tid = threadIdx.x, lane = tid&63, wave = tid>>6;
  const float4* h4 = (const float4*)(hid + b*2048);
  const float4* w4 = (const float4*)(w2 + (long)j*2048);
  float4 a0 = h4[tid*2], a1 = h4[tid*2+1];
  float4 c0 = w4[tid*2], c1 = w4[tid*2+1];
  float s = a0.x*c0.x+a0.y*c0.y+a0.z*c0.z+a0.w*c0.w
          + a1.x*c1.x+a1.y*c1.y+a1.z*c1.z+a1.w*c1.w;
  #pragma unroll
  for (int off=32; off; off>>=1) s += __shfl_down(s, off);
  __shared__ float wsum[4];
  if (lane==0) wsum[wave] = s;
  __syncthreads();
  if (tid==0) lg[b*25+j] = wsum[0]+wsum[1]+wsum[2]+wsum[3] + b2[j];
}

// ---------------- softmax over 25 logits -> kw[b][32] ----------------
__global__ __launch_bounds__(64) void k_smax(const float* lg, float* kw)
{
  int b = threadIdx.x;
  if (b < 8) {
    float mx = -1e30f;
    for (int j=0;j<25;++j) mx = fmaxf(mx, lg[b*25+j]);
    float e[25], s = 0.f;
    for (int j=0;j<25;++j){ e[j]=__expf(lg[b*25+j]-mx); s+=e[j]; }
    float inv = 1.f/s;
    for (int j=0;j<25;++j) kw[b*32+j] = e[j]*inv;
  }
}

// ---------------- generic TN bf16 MFMA GEMM (counted-vmcnt pipeline; KU sub-slices per barrier) ----------------
// OP 0: QKV   flat 768:  b=wg&7, which=wg>>8, xy=(wg>>3)&31   [KU=2: BK=64]
// OP 1: Wo    flat 512:  b=wg&7, xy=wg>>3 (8m x 8n)           [KU=2]
// OP 2: enh   flat 512:  b=wg&7, kg=(wg>>3)>>5, xy=(wg>>3)&31 [KU=2, fused split-K reduce]
// OP 3: gate1 flat 576:  b=wg&7, n=(wg>>3)&7, tap=(wg>>3)>>3  [KU=2]
template<int OP, int BM, int BN, int WAVES_M, int KSTEPS, int KU>
__global__ __launch_bounds__(256)
void k_gemm(KParams p)
{
  constexpr int WAVES_N = 4/WAVES_M;
  constexpr int MT = BM/(WAVES_M*16);
  constexpr int NT = BN/(WAVES_N*16);
  constexpr int ACH = (BM*4 + 255)/256;
  constexpr int BCH = (BN*4 + 255)/256;
  constexpr int WPS = KU*((BM*4)/256 + BCH);   // min per-wave loads per STAGE
  constexpr int NBUF = (KU==2) ? 2 : 3;
  __shared__ bf16 As[NBUF][KU*BM*32];
  __shared__ bf16 Bs[NBUF][KU*BN*32];
  const int tid = threadIdx.x, lane = tid&63, wave = tid>>6;
  const int g = lane>>4, l15 = lane&15;
  const int wm = wave % WAVES_M, wn = wave / WAVES_M;

  int b, which = 0, tapc = 0, kg = 0, m0, n0, xyv = 0;
  const bf16 *Aptr, *Bptr;
  long ldb, lda;
  const int wg = blockIdx.x;
  if constexpr (OP==0) {
    b = wg&7; which = wg>>8;
    int xy = (wg>>3)&31;
    m0 = (xy>>3)*BM; n0 = (xy&7)*BN;
    Aptr = (const bf16*)(p.ws+OFF_WBF) + (long)which*262144;
    Bptr = (const bf16*)(p.ws+OFF_CATSEQ) + (long)b*1048576 + (which?512:0);
    ldb = 1024; lda = 512;
  } else if constexpr (OP==1) {
    b = wg&7;
    int xy = wg>>3;
    m0 = (xy>>3)*BM; n0 = (xy&7)*BN;
    Aptr = (const bf16*)(p.ws+OFF_WBF) + 3L*262144;
    Bptr = (const bf16*)(p.ws+OFF_CTX) + (long)b*524288;
    ldb = 512; lda = 512;
  } else if constexpr (OP==2) {
    b = wg&7;
    int loc = wg>>3;
    kg = loc>>5;
    int xy = loc&31;
    xyv = xy;
    m0 = (xy>>3)*BM; n0 = (xy&7)*BN;
    Aptr = (const bf16*)(p.ws+OFF_ENHW);
    Bptr = (const bf16*)(p.ws+OFF_F2) + (long)b*524288;
    ldb = 512; lda = 512;
  } else {
    b = wg&7;
    int loc = wg>>3;
    tapc = loc>>3;
    m0 = 0; n0 = (loc&7)*BN;
    Aptr = (const bf16*)(p.ws+OFF_GW1R) + (long)tapc*32768;
    Bptr = (const bf16*)(p.ws+OFF_CATSEQ) + (long)b*1048576;
    ldb = 1024; lda = 1024;
  }
  const bf16* zp = (const bf16*)(p.ws+OFF_ZP);

  // ---- hoisted per-thread staging state ----
  int tap = (OP==2) ? (kg*72)>>4 : tapc;
  int kcc = (OP==2) ? (kg*72)&15 : 0;
  const bf16* pA[ACH];
  const bf16* pB[BCH];
  bool aact[ACH];
  bool bval[BCH];
  int bpp[BCH], bss8[BCH];
  int dstA[ACH], dstB[BCH];
  #pragma unroll
  for (int i=0;i<ACH;++i) {
    int cc_ = tid + 256*i;
    aact[i] = cc_ < BM*4;
    int c = aact[i] ? cc_ : 0;
    int row = c>>2, slot = c&3, ss = slot ^ ((row>>1)&3);
    dstA[i] = ((c-lane))*8;
    if constexpr (OP==2) pA[i] = Aptr + (long)tap*262144 + (long)(m0+row)*lda + kcc*32 + ss*8;
    else                 pA[i] = Aptr + (long)(m0+row)*lda + ss*8;
  }
  #pragma unroll
  for (int i=0;i<BCH;++i) {
    int c = tid + 256*i;
    int row = c>>2, slot = c&3, ss = slot ^ ((row>>1)&3);
    dstB[i] = ((c-lane))*8;
    bss8[i] = ss*8;
    if constexpr (OP==2 || OP==3) {
      int pp = n0 + row; bpp[i] = pp;
      int hh = (pp>>5) + tap/3 - 1, ww = (pp&31) + tap%3 - 1;
      bool v = ((unsigned)hh < 32u) && ((unsigned)ww < 32u);
      bval[i] = v;
      pB[i] = v ? (Bptr + (long)(hh*32+ww)*ldb + kcc*32 + ss*8) : zp;
    } else {
      bval[i] = true;
      pB[i] = Bptr + (long)(n0+row)*ldb + ss*8;
    }
  }

  auto ADV = [&]() {
    if constexpr (OP==2) {
      ++kcc;
      if (kcc == 16) {
        kcc = 0; ++tap;
        int t3 = tap/3, tm = tap%3;
        #pragma unroll
        for (int i=0;i<ACH;++i) pA[i] += 262144 - 480;
        #pragma unroll
        for (int i=0;i<BCH;++i) {
          int hh = (bpp[i]>>5) + t3 - 1, ww = (bpp[i]&31) + tm - 1;
          bool v = ((unsigned)hh < 32u) && ((unsigned)ww < 32u);
          bval[i] = v;
          pB[i] = v ? (Bptr + (long)(hh*32+ww)*ldb + bss8[i]) : zp;
        }
      } else {
        #pragma unroll
        for (int i=0;i<ACH;++i) pA[i] += 32;
        #pragma unroll
        for (int i=0;i<BCH;++i) pB[i] += bval[i] ? 32 : 0;
      }
    } else if constexpr (OP==3) {
      #pragma unroll
      for (int i=0;i<ACH;++i) pA[i] += 32;
      #pragma unroll
      for (int i=0;i<BCH;++i) pB[i] += bval[i] ? 32 : 0;
    } else {
      #pragma unroll
      for (int i=0;i<ACH;++i) pA[i] += 32;
      #pragma unroll
      for (int i=0;i<BCH;++i) pB[i] += 32;
    }
  };

  auto STAGE = [&](int buf) {
    #pragma unroll
    for (int u=0;u<KU;++u) {
      #pragma unroll
      for (int i=0;i<ACH;++i) if (aact[i]) gload16(pA[i], As[buf] + u*BM*32 + dstA[i]);
      #pragma unroll
      for (int i=0;i<BCH;++i) gload16(pB[i], Bs[buf] + u*BN*32 + dstB[i]);
      ADV();
    }
  };

  f32x4 acc[MT][NT] = {};

  auto COMPUTE = [&](int cur) {
    #pragma unroll
    for (int u=0;u<KU;++u) {
      bf16x8 af[MT], bq_[NT];
      #pragma unroll
      for (int mt=0; mt<MT; ++mt) {
        int row = wm*MT*16 + mt*16 + l15;
        af[mt] = *(const bf16x8*)&As[cur][u*BM*32 + row*32 + 8*(g ^ ((row>>1)&3))];
      }
      #pragma unroll
      for (int nt=0; nt<NT; ++nt) {
        int row = wn*NT*16 + nt*16 + l15;
        bq_[nt] = *(const bf16x8*)&Bs[cur][u*BN*32 + row*32 + 8*(g ^ ((row>>1)&3))];
      }
      __builtin_amdgcn_s_setprio(1);
      #pragma unroll
      for (int mt=0; mt<MT; ++mt)
        #pragma unroll
        for (int nt=0; nt<NT; ++nt)
          acc[mt][nt] = __builtin_amdgcn_mfma_f32_16x16x32_bf16(af[mt], bq_[nt], acc[mt][nt], 0,0,0);
      __builtin_amdgcn_s_setprio(0);
    }
  };

  if constexpr (KU==2) {
    STAGE(0);
    int cur = 0;
    for (int ks = 0; ks < KSTEPS; ++ks) {
      if (ks+1 < KSTEPS) { STAGE(cur^1); waitvm<WPS>(); }
      else               { waitvm<0>(); }
      __builtin_amdgcn_s_barrier();
      __builtin_amdgcn_sched_barrier(0);
      COMPUTE(cur);
      __builtin_amdgcn_s_barrier();
      cur ^= 1;
    }
  } else {
    STAGE(0);
    STAGE(1);
    int cur = 0, stg = 2;
    for (int ks = 0; ks < KSTEPS; ++ks) {
      if (ks+2 < KSTEPS)      { STAGE(stg); stg = (stg==2)?0:stg+1; waitvm<2*WPS>(); }
      else if (ks+1 < KSTEPS) { waitvm<WPS>(); }
      else                    { waitvm<0>(); }
      __builtin_amdgcn_s_barrier();
      __builtin_amdgcn_sched_barrier(0);
      COMPUTE(cur);
      __builtin_amdgcn_s_barrier();
      cur = (cur==2)?0:cur+1;
    }
  }

  #pragma unroll
  for (int mt=0; mt<MT; ++mt) {
    #pragma unroll
    for (int nt=0; nt<NT; ++nt) {
      int mb = m0 + wm*MT*16 + mt*16 + 4*g;
      int n = n0 + wn*NT*16 + nt*16 + l15;
      if constexpr (OP==0) {
        const float* bias = which==0?p.bq: which==1?p.bk:p.bv;
        float v4[4];
        #pragma unroll
        for (int reg=0; reg<4; ++reg) {
          float v = acc[mt][nt][reg] + bias[mb+reg];
          if (which==0) v *= 0.18033688011112042f;   // 0.125 * log2(e)
          v4[reg] = v;
        }
        int h = mb>>6, d0 = mb&63;
        if (which==2) {
          #pragma unroll
          for (int reg=0; reg<4; ++reg)
            ((bf16*)(p.ws+OFF_VT))[((long)(b*8+h)*64 + d0+reg)*1024 + n] = (bf16)v4[reg];
        } else {
          bf16* dst = (bf16*)(p.ws + (which==0?OFF_Q:OFF_K));
          bf16x4 o = {(bf16)v4[0],(bf16)v4[1],(bf16)v4[2],(bf16)v4[3]};
          *(bf16x4*)(dst + ((long)(b*8+h)*1024 + n)*64 + d0) = o;
        }
      } else {
        #pragma unroll
        for (int reg=0; reg<4; ++reg) {
          int m = mb + reg;
          float v = acc[mt][nt][reg];
          if constexpr (OP==1) {
            v += p.bo[m];
            ((bf16*)(p.ws+OFF_FF))[((long)(b*512+m))*1024 + n] = (bf16)v;
          } else if constexpr (OP==2) {
            float* part = (float*)(p.ws+OFF_Q) + (long)kg*4194304;
            part[((long)b*512+m)*1024 + n] = v;
          } else {
            ((float*)(p.ws+OFF_G1P))[((long)((tapc*8+b)*32+m))*1024 + n] = v;
          }
        }
      }
    }
  }

  // ---- enh fused split-K reduce: second finisher combines other partial + own regs ----
  if constexpr (OP==2) {
    __threadfence();
    __shared__ int done_s;
    if (tid==0) done_s = atomicAdd((int*)(p.ws+OFF_POOL) + (b*32 + xyv), 1);
    __syncthreads();
    if (done_s == 1) {
      __threadfence();   // acquire: other block's partial writes visible
      const float* oth = (const float*)(p.ws+OFF_Q) + (long)(kg^1)*4194304;
      const float* chs = (const float*)(p.ws+OFF_CHS);
      #pragma unroll
      for (int mt=0; mt<MT; ++mt) {
        #pragma unroll
        for (int nt=0; nt<NT; ++nt) {
          #pragma unroll
          for (int reg=0; reg<4; ++reg) {
            int m = m0 + wm*MT*16 + mt*16 + 4*g + reg;
            int n = n0 + wn*NT*16 + nt*16 + l15;
            float v = acc[mt][nt][reg] + oth[((long)b*512+m)*1024 + n];
            float y = v*chs[m] + chs[512+m];
            p.out[((long)(b*512+m))*1024 + n] = y/(1.f+__expf(-y));
          }
        }
      }
    }
  }
}

// ---------------- flash attention (KVBLK=64, counted-vmcnt pipeline, no-max softmax, exp2) ----------------
__global__ __launch_bounds__(256)
void k_attn(KParams p)
{
  const bf16* Q = (const bf16*)(p.ws+OFF_Q);
  const bf16* K = (const bf16*)(p.ws+OFF_K);
  const bf16* V = (const bf16*)(p.ws+OFF_VT);
  bf16* ctx = (bf16*)(p.ws+OFF_CTX);
  int wg = blockIdx.x;
  int bh = (wg&7)*8 + (wg>>7);
  int qt = (wg>>3)&15;
  int b = bh>>3, h = bh&7;
  int tid = threadIdx.x, lane = tid&63, wave = tid>>6, g = lane>>4, l15 = lane&15;
  __shared__ bf16 Ks[2][64*64];
  __shared__ bf16 Vs[2][64*64];
  __shared__ bf16 Ps[4][16*64];
  const bf16* Qw = Q + ((long)bh*1024 + qt*64 + wave*16)*64;
  bf16x8 qf[2];
  qf[0] = *(const bf16x8*)(Qw + l15*64 + g*8);
  qf[1] = *(const bf16x8*)(Qw + l15*64 + 32 + g*8);
  const bf16* Kb = K + (long)bh*65536;
  const bf16* Vb = V + (long)bh*65536;
  float lrp[4] = {0,0,0,0};
  f32x4 cacc[4] = {};

  const bf16* pK[2]; const bf16* pV[2];
  int dstK[2], dstV[2];
  {
    int c = tid;
    int krow = c>>3, kslot = c&7, kss = kslot ^ (krow&7);
    pK[0] = Kb + (long)krow*64 + kss*8;
    pK[1] = Kb + (long)(krow+32)*64 + (kslot ^ ((krow+32)&7))*8;
    int d = c>>3, ss2 = kslot ^ (d&7);
    pV[0] = Vb + (long)d*1024 + ss2*8;
    pV[1] = Vb + (long)(d+32)*1024 + ss2*8;
    dstK[0] = (tid-lane)*8;       dstK[1] = (tid-lane+256)*8;
    dstV[0] = (tid-lane)*8;       dstV[1] = (tid-lane+256)*8;
  }
  auto STAGE = [&](int buf) {
    gload16(pK[0], Ks[buf] + dstK[0]);
    gload16(pK[1], Ks[buf] + dstK[1]);
    gload16(pV[0], Vs[buf] + dstV[0]);
    gload16(pV[1], Vs[buf] + dstV[1]);
  };
  auto ADV = [&]() {
    pK[0] += 4096; pK[1] += 4096;
    pV[0] += 64;   pV[1] += 64;
  };

  STAGE(0); ADV();
  int cur = 0;
  for (int step = 0; step < 16; ++step) {
    if (step < 15) { STAGE(cur^1); ADV(); waitvm<4>(); }
    else           { waitvm<0>(); }
    __builtin_amdgcn_s_barrier();
    __builtin_amdgcn_sched_barrier(0);
    f32x4 s0 = {}, s1 = {}, s2 = {}, s3 = {};
    __builtin_amdgcn_s_setprio(1);
    {
      int r0 = l15, r1 = 16+l15, r2 = 32+l15, r3 = 48+l15;
      #pragma unroll
      for (int ks2=0; ks2<2; ++ks2) {
        bf16x8 kf0 = *(const bf16x8*)&Ks[cur][r0*64 + 8*((4*ks2+g)^(r0&7))];
        bf16x8 kf1 = *(const bf16x8*)&Ks[cur][r1*64 + 8*((4*ks2+g)^(r1&7))];
        bf16x8 kf2 = *(const bf16x8*)&Ks[cur][r2*64 + 8*((4*ks2+g)^(r2&7))];
        bf16x8 kf3 = *(const bf16x8*)&Ks[cur][r3*64 + 8*((4*ks2+g)^(r3&7))];
        s0 = __builtin_amdgcn_mfma_f32_16x16x32_bf16(qf[ks2], kf0, s0, 0,0,0);
        s1 = __builtin_amdgcn_mfma_f32_16x16x32_bf16(qf[ks2], kf1, s1, 0,0,0);
        s2 = __builtin_amdgcn_mfma_f32_16x16x32_bf16(qf[ks2], kf2, s2, 0,0,0);
        s3 = __builtin_amdgcn_mfma_f32_16x16x32_bf16(qf[ks2], kf3, s3, 0,0,0);
      }
    }
    __builtin_amdgcn_s_setprio(0);
    bf16* Pw = Ps[wave];
    #pragma unroll
    for (int r=0;r<4;++r) {
      float p0 = __builtin_amdgcn_exp2f(s0[r]);
      float p1 = __builtin_amdgcn_exp2f(s1[r]);
      float p2 = __builtin_amdgcn_exp2f(s2[r]);
      float p3 = __builtin_amdgcn_exp2f(s3[r]);
      int q = 4*g + r;
      int xr = 8*(q&7);
      Pw[q*64 + ((     l15) ^ xr)] = (bf16)p0;
      Pw[q*64 + ((16 + l15) ^ xr)] = (bf16)p1;
      Pw[q*64 + ((32 + l15) ^ xr)] = (bf16)p2;
      Pw[q*64 + ((48 + l15) ^ xr)] = (bf16)p3;
      lrp[r] += (p0+p1)+(p2+p3);
    }
    bf16x8 pa0 = *(const bf16x8*)&Pw[l15*64 + 8*((  g)^(l15&7))];
    bf16x8 pa1 = *(const bf16x8*)&Pw[l15*64 + 8*((4+g)^(l15&7))];
    __builtin_amdgcn_s_setprio(1);
    #pragma unroll
    for (int nt=0;nt<4;++nt) {
      int d = nt*16 + l15;
      bf16x8 vf0 = *(const bf16x8*)&Vs[cur][d*64 + 8*((  g)^(d&7))];
      bf16x8 vf1 = *(const bf16x8*)&Vs[cur][d*64 + 8*((4+g)^(d&7))];
      cacc[nt] = __builtin_amdgcn_mfma_f32_16x16x32_bf16(pa0, vf0, cacc[nt], 0,0,0);
      cacc[nt] = __builtin_amdgcn_mfma_f32_16x16x32_bf16(pa1, vf1, cacc[nt], 0,0,0);
    }
    __builtin_amdgcn_s_setprio(0);
    __builtin_amdgcn_s_barrier();
    cur ^= 1;
  }
  float lr[4];
  #pragma unroll
  for (int r=0;r<4;++r) {
    float s = lrp[r];
    s += __shfl_xor(s, 1);
    s += __shfl_xor(s, 2);
    s += __shfl_xor(s, 4);
    s += __shfl_xor(s, 8);
    lr[r] = s;
  }
  #pragma unroll
  for (int nt=0;nt<4;++nt) {
    #pragma unroll
    for (int r=0;r<4;++r) {
      int q = qt*64 + wave*16 + 4*g + r;
      int cc = h*64 + nt*16 + l15;
      ctx[((long)(b*1024+q))*512 + cc] = (bf16)(cacc[nt][r] / lr[r]);
    }
  }
}

// ---------------- gate1 tap-partial reduce + bias + relu ----------------
__global__ __launch_bounds__(256) void k_g1red(KParams p)
{
  long o = (long)blockIdx.x*256 + threadIdx.x;   // [b][m][n], 262144
  const float* part = (const float*)(p.ws+OFF_G1P);
  int m = (int)((o >> 10) & 31);
  float a = p.gb1[m];
  #pragma unroll
  for (int t=0;t<9;++t) a += part[(long)t*262144 + o];
  ((float*)(p.ws+OFF_Y1))[o] = fmaxf(a, 0.f);
}

// ---------------- gate2 + sigmoid + sum -> gsum[b][p] ----------------
__global__ __launch_bounds__(256)
void k_g2(KParams p, const float* gw2, const float* gb2)
{
  __shared__ float st[3*32*32];
  __shared__ float sg[2][32];
  int h = blockIdx.x, b = blockIdx.y;
  const float* y1 = (const float*)(p.ws+OFF_Y1) + (long)b*32768;
  int tid = threadIdx.x;
  for (int c = tid; c < 768; c += 256) {
    int e = c*4;
    int hr = e>>10, hid = (e>>5)&31, w = e&31;
    int hh = h + hr - 1;
    float4 v = {0,0,0,0};
    if ((unsigned)hh < 32u) v = *(const float4*)(y1 + hid*1024 + hh*32 + w);
    *(float4*)&st[e] = v;
  }
  __syncthreads();
  if (tid < 64) {
    int gg = tid>>5, w = tid&31;
    float acc = gb2[gg];
    for (int hid=0; hid<32; ++hid) {
      #pragma unroll
      for (int u=0;u<3;++u) {
        #pragma unroll
        for (int v=0;v<3;++v) {
          int ww = w + v - 1;
          if ((unsigned)ww < 32u)
            acc += st[(u*32+hid)*32 + ww] * gw2[((gg*32+hid)*3+u)*3+v];
        }
      }
    }
    sg[gg][w] = 1.f/(1.f+__expf(-acc));
  }
  __syncthreads();
  if (tid < 32) ((float*)(p.ws+OFF_GSUM))[b*1024 + h*32 + tid] = sg[0][tid]+sg[1][tid];
}

// ---------------- dynamic 5x5 depthwise conv + gated fuse -> fused2[b][p][c] ----------------
__global__ __launch_bounds__(512)
void k_dyn(KParams p)
{
  __shared__ float ffs[16*1024];
  int ct = blockIdx.x;            // 0..31
  int b  = blockIdx.y;            // 0..7
  int c0 = ct*16;
  int t = threadIdx.x;            // 512
  const bf16* ffg = (const bf16*)(p.ws+OFF_FF) + ((long)(b*512 + c0))*1024;
  #pragma unroll
  for (int k2 = 0; k2 < 4; ++k2) {
    int chunk = t + 512*k2;
    int c = chunk >> 7, j = chunk & 127;
    bf16x8 v = *(const bf16x8*)(ffg + (long)c*1024 + j*8);
    float* d = ffs + c*1024 + j*8;
    #pragma unroll
    for (int e=0;e<8;++e) d[e] = (float)v[e];
  }
  const float* kwp = (const float*)(p.ws+OFF_KW) + b*32;
  float kk[25];
  #pragma unroll
  for (int j=0;j<25;++j) kk[j] = kwp[j];
  __syncthreads();
  int w = t & 31;
  int h0 = t >> 5;                // 0..15
  #pragma unroll
  for (int pass=0; pass<2; ++pass) {
    int h = h0 + pass*16;
    int pos = h*32 + w;
    float gsw = ((const float*)(p.ws+OFF_GSUM))[b*1024 + pos];
    const bf16* cs = (const bf16*)(p.ws+OFF_CATSEQ) + ((long)(b*1024) + pos)*1024 + c0;
    bf16x8 vv0 = *(const bf16x8*)cs;
    bf16x8 vv1 = *(const bf16x8*)(cs + 8);
    bf16x8 rr0 = *(const bf16x8*)(cs + 512);
    bf16x8 rr1 = *(const bf16x8*)(cs + 520);
    bf16 outv[16];
    #pragma unroll
    for (int c=0;c<16;++c) {
      float dyn = 0.f;
      #pragma unroll
      for (int u=0;u<5;++u) {
        int hh = h+u-2;
        bool okh = (unsigned)hh < 32u;
        #pragma unroll
        for (int v=0;v<5;++v) {
          int ww = w+v-2;
          bool ok = okh && ((unsigned)ww < 32u);
          float fv = ffs[c*1024 + (hh&31)*32 + (ww&31)];
          dyn += (ok ? fv : 0.f) * kk[u*5+v];
        }
      }
      float resid = (c < 8) ? ((float)vv0[c] + (float)rr0[c])
                            : ((float)vv1[c-8] + (float)rr1[c-8]);
      float val = gsw*dyn + resid;
      outv[c] = (bf16)val;
    }
    bf16* f2 = (bf16*)(p.ws+OFF_F2) + ((long)(b*1024 + pos))*512 + c0;
    *(bf16x8*)f2       = *(bf16x8*)&outv[0];
    *((bf16x8*)f2 + 1) = *(bf16x8*)&outv[8];
  }
}

extern "C" void kernel_launch(void* const* d_in, const int* in_sizes, int n_in,
                              void* d_out, int out_size, void* d_ws, size_t ws_size,
                              hipStream_t stream)
{
  char* ws = (char*)d_ws;
  KParams p;
  p.vi = (const float*)d_in[0];  p.ir = (const float*)d_in[1];
  p.bq = (const float*)d_in[7];  p.bk = (const float*)d_in[9];
  p.bv = (const float*)d_in[11]; p.bo = (const float*)d_in[13];
  p.gb1 = (const float*)d_in[15];
  p.ws = ws; p.out = (float*)d_out;

  k_prep<<<6692,256,0,stream>>>(p.vi, p.ir,
      (const float*)d_in[6],(const float*)d_in[8],(const float*)d_in[10],(const float*)d_in[12],
      (const float*)d_in[18],(const float*)d_in[14],
      (const float*)d_in[19],(const float*)d_in[20],(const float*)d_in[21],(const float*)d_in[22],(const float*)d_in[23],
      (bf16*)(ws+OFF_WBF),(bf16*)(ws+OFF_ENHW),(bf16*)(ws+OFF_GW1R),(float*)(ws+OFF_CHS),(float*)(ws+OFF_ZP),
      (int*)(ws+OFF_POOL),(bf16*)(ws+OFF_CATSEQ),(float*)(ws+OFF_Y1));
  k_mlp1<<<128,256,0,stream>>>((const float*)(ws+OFF_Y1),(const float*)d_in[2],(const float*)d_in[3],(float*)(ws+OFF_HID));
  k_mlp2a<<<200,256,0,stream>>>((const float*)(ws+OFF_HID),(const float*)d_in[4],(const float*)d_in[5],(float*)(ws+OFF_G1P));
  k_smax<<<1,64,0,stream>>>((const float*)(ws+OFF_G1P),(float*)(ws+OFF_KW));
  k_gemm<0,128,128,2,8,2><<<768,256,0,stream>>>(p);
  k_attn<<<1024,256,0,stream>>>(p);
  k_gemm<1,64,128,2,8,2><<<512,256,0,stream>>>(p);
  k_gemm<3,32,128,1,16,2><<<576,256,0,stream>>>(p);
  k_g1red<<<1024,256,0,stream>>>(p);
  k_g2<<<dim3(32,8),256,0,stream>>>(p,(const float*)d_in[16],(const float*)d_in[17]);
  k_dyn<<<dim3(32,8),512,0,stream>>>(p);
  k_gemm<2,128,128,2,36,2><<<512,256,0,stream>>>(p);
}

// Round 19
// 220.246 us; speedup vs baseline: 1.4669x; 1.4669x over previous
//
#include <hip/hip_runtime.h>

typedef __bf16 bf16;
typedef __attribute__((ext_vector_type(2))) __bf16 bf16x2;
typedef __attribute__((ext_vector_type(4))) __bf16 bf16x4;
typedef __attribute__((ext_vector_type(8))) __bf16 bf16x8;
typedef __attribute__((ext_vector_type(4))) float f32x4;

// ---------------- workspace layout (bytes) ----------------
constexpr size_t OFF_CATSEQ = 0;          // 16777216  [b][p][c(0:512 vi,512:1024 ir)] bf16
constexpr size_t OFF_WBF    = 16777216;   // 2097152   Wq,Wk,Wv,Wo bf16 [co][c]
constexpr size_t OFF_ENHW   = 18874368;   // 4718592   enh_w repacked [t][co][ci] bf16
constexpr size_t OFF_GW1R   = 23592960;   // 589824    gate_w1 repacked [t][hid][ci] bf16
constexpr size_t OFF_CHS    = 24182784;   // 4096      bn scale[512], shift[512]
constexpr size_t OFF_ZP     = 24186880;   // 256       zero page
constexpr size_t OFF_POOL   = 24187136;   // 16384     (unused)
constexpr size_t OFF_HID    = 24203520;   // 65536
constexpr size_t OFF_KW     = 24269056;   // 1024
constexpr size_t OFF_Q      = 24270080;   // 8388608  [b][h][p][d] bf16 (x0.125*log2e); later: enh partials (2x16.78MB f32)
constexpr size_t OFF_K      = 32658688;   // 8388608  [b][h][p][d] bf16
constexpr size_t OFF_VT     = 41047296;   // 8388608  [b][h][d][p] bf16; reused as enh partial kg=1
constexpr size_t OFF_CTX    = 49435904;   // 8388608  [b][p][c] bf16
constexpr size_t OFF_FF     = 57824512;   // 8388608  fused_feat [b][c][p] bf16
constexpr size_t OFF_G1P    = 66213120;   // 9437184  gate1 partials [t][b][32][1024] f32 (early: mlp2 logits)
constexpr size_t OFF_Y1     = 75650304;   // 1048576  y1 [b][32][1024] f32 (early: pool partials [b*8+pt][1024])
constexpr size_t OFF_GSUM   = 76698880;   // 32768    [b][p] f32
constexpr size_t OFF_F2     = 76731648;   // 8388608  fused2 [b][p][c] bf16
// total 85120256 bytes

struct KParams {
  const float *vi, *ir, *bq, *bk, *bv, *bo, *gb1;
  char* ws;
  float* out;
};

__device__ __forceinline__ void gload16(const void* g, void* l) {
  __builtin_amdgcn_global_load_lds(
      (const __attribute__((address_space(1))) unsigned int*)g,
      (__attribute__((address_space(3))) unsigned int*)l, 16, 0, 0);
}

template<int N> __device__ __forceinline__ void waitvm() {
  if constexpr (N==0) asm volatile("s_waitcnt vmcnt(0)" ::: "memory");
  else if constexpr (N==1) asm volatile("s_waitcnt vmcnt(1)" ::: "memory");
  else if constexpr (N==2) asm volatile("s_waitcnt vmcnt(2)" ::: "memory");
  else if constexpr (N==3) asm volatile("s_waitcnt vmcnt(3)" ::: "memory");
  else if constexpr (N==4) asm volatile("s_waitcnt vmcnt(4)" ::: "memory");
  else if constexpr (N==6) asm volatile("s_waitcnt vmcnt(6)" ::: "memory");
  else if constexpr (N==8) asm volatile("s_waitcnt vmcnt(8)" ::: "memory");
  else asm volatile("s_waitcnt vmcnt(12)" ::: "memory");
}

// ---------------- merged prep: QKVO cast, bn-fold, zero page, enh/gw1 repack, cat+pool ----------------
// blocks [0,4100): scalar range; [4100,4612): enh repack; [4612,4644): gw1 repack; [4644,6692): cat
__global__ __launch_bounds__(256) void k_prep(const float* vi, const float* ir,
                        const float* Wq, const float* Wk, const float* Wv, const float* Wo,
                        const float* enh_w, const float* gw1,
                        const float* enh_b, const float* gamma, const float* beta,
                        const float* mean, const float* var,
                        bf16* wbf, bf16* enhw, bf16* gw1r, float* chs, float* zp,
                        bf16* cat, float* pool)
{
  __shared__ float ld[9216];
  int blk = blockIdx.x, tid = threadIdx.x;
  if (blk < 4100) {
    long i = (long)blk*256 + tid;
    if (i < 1048576) {
      int which = (int)(i >> 18); long r = i & 262143;
      const float* s = which==0?Wq: which==1?Wk: which==2?Wv:Wo;
      wbf[i] = (bf16)s[r];
    } else if (i < 1048576+512) {
      int c = (int)(i - 1048576);
      float sc = gamma[c]*rsqrtf(var[c]+1e-5f);
      chs[c] = sc; chs[512+c] = (enh_b[c]-mean[c])*sc + beta[c];
    } else if (i < 1048576+512+64) {
      zp[i - (1048576+512)] = 0.f;
    }
  } else if (blk < 4100+512) {
    int co = blk - 4100;
    const float* src = enh_w + (long)co*4608;     // [ci][3][3] contiguous
    #pragma unroll
    for (int it=0; it<18; ++it) ld[tid + 256*it] = src[tid + 256*it];
    __syncthreads();
    #pragma unroll
    for (int t=0;t<9;++t) {
      int ci = tid*2;
      bf16x2 v = { (bf16)ld[ci*9 + t], (bf16)ld[(ci+1)*9 + t] };
      ((bf16x2*)(enhw + (long)t*262144 + (long)co*512))[tid] = v;
    }
  } else if (blk < 4100+512+32) {
    int hid = blk - (4100+512);
    const float* src = gw1 + (long)hid*9216;      // [ci=1024][3][3]
    #pragma unroll
    for (int it=0; it<36; ++it) ld[tid + 256*it] = src[tid + 256*it];
    __syncthreads();
    #pragma unroll
    for (int t=0;t<9;++t) {
      int ci = tid*4;
      bf16x4 v = { (bf16)ld[ci*9+t], (bf16)ld[(ci+1)*9+t],
                   (bf16)ld[(ci+2)*9+t], (bf16)ld[(ci+3)*9+t] };
      *(bf16x4*)(gw1r + (long)t*32768 + (long)hid*1024 + ci) = v;
    }
  } else {
    int idx = blk - (4100+512+32);
    int pt = idx&7, ct = (idx>>3)&31, b = idx>>8;
    const float* src = (ct < 16) ? vi : ir;
    int c0 = (ct & 15) * 32;
    int p0 = pt * 128;
    for (int it = 0; it < 4; ++it) {
      int row = it*8 + (tid>>5);
      int pc  = (tid & 31) * 4;
      float4 v = *(const float4*)(src + ((long)(b*512 + c0 + row))*1024 + p0 + pc);
      ld[row*129+pc+0]=v.x; ld[row*129+pc+1]=v.y; ld[row*129+pc+2]=v.z; ld[row*129+pc+3]=v.w;
    }
    __syncthreads();
    int p = tid >> 1, half = tid & 1;
    bf16x8 o0, o1;
    #pragma unroll
    for (int j = 0; j < 8; ++j) o0[j] = (bf16)ld[(half*16 + j)*129 + p];
    #pragma unroll
    for (int j = 0; j < 8; ++j) o1[j] = (bf16)ld[(half*16 + 8 + j)*129 + p];
    long ccol = (ct<16 ? 0 : 512) + c0 + half*16;
    bf16* dst = cat + ((long)(b*1024 + p0 + p))*1024 + ccol;
    *(bf16x8*)dst       = o0;
    *((bf16x8*)dst + 1) = o1;
    // fused pool partial
    {
      int c = tid>>3, j = tid&7;
      float s = 0.f;
      #pragma unroll
      for (int i=0;i<16;++i) s += ld[c*129 + j*16+i];
      s += __shfl_down(s, 4);
      s += __shfl_down(s, 2);
      s += __shfl_down(s, 1);
      if (j==0) {
        int pc_ = (ct<16 ? 0 : 512) + c0 + c;
        pool[((long)(b*8+pt))*1024 + pc_] = s;
      }
    }
  }
}

// ---------------- mlp1: wave-per-row, partial-sum staging (partials [b*8+pt][1024], vi+ir halves) ----------------
__global__ __launch_bounds__(256) void k_mlp1(const float* partial, const float* w1, const float* b1, float* hid)
{
  __shared__ float pl[8*512];
  int tid = threadIdx.x;
  const float4* pp4 = (const float4*)partial;   // [b*8+pt][256 float4]
  #pragma unroll
  for (int k=0;k<4;++k) {
    int j = tid + 256*k;          // b*128 + c4
    int b = j>>7, c4 = j&127;
    float4 s = {0,0,0,0};
    #pragma unroll
    for (int pt=0;pt<8;++pt) {
      float4 v = pp4[(b*8+pt)*256 + c4];
      float4 w = pp4[(b*8+pt)*256 + 128 + c4];
      s.x+=v.x+w.x; s.y+=v.y+w.y; s.z+=v.z+w.z; s.w+=v.w+w.w;
    }
    float4 o = {s.x*(1.f/1024.f), s.y*(1.f/1024.f), s.z*(1.f/1024.f), s.w*(1.f/1024.f)};
    ((float4*)pl)[j] = o;
  }
  __syncthreads();
  int lane = tid&63, wave = tid>>6;
  #pragma unroll
  for (int rr=0; rr<4; ++rr) {
    int row = (blockIdx.x*4 + wave)*4 + rr;
    const float* wr = w1 + (long)row*512;
    float acc[8] = {};
    #pragma unroll
    for (int e=0;e<8;++e) {
      int c = lane + 64*e;
      float w = wr[c];
      #pragma unroll
      for (int b=0;b<8;++b) acc[b] += w * pl[b*512+c];
    }
    #pragma unroll
    for (int b=0;b<8;++b) {
      float s = acc[b];
      #pragma unroll
      for (int off=32; off; off>>=1) s += __shfl_down(s, off);
      if (lane==0) hid[b*2048 + row] = fmaxf(s + b1[row], 0.f);
    }
  }
}

// ---------------- mlp2a: one block per (b,j) logit ----------------
__global__ __launch_bounds__(256) void k_mlp2a(const float* hid, const float* w2, const float* b2, float* lg)
{
  int blk = blockIdx.x; int b = blk/25, j = blk%25;
  int tid = threadIdx.x, lane = tid&63, wave = tid>>6;
  const float4* h4 = (const float4*)(hid + b*2048);
  const float4* w4 = (const float4*)(w2 + (long)j*2048);
  float4 a0 = h4[tid*2], a1 = h4[tid*2+1];
  float4 c0 = w4[tid*2], c1 = w4[tid*2+1];
  float s = a0.x*c0.x+a0.y*c0.y+a0.z*c0.z+a0.w*c0.w
          + a1.x*c1.x+a1.y*c1.y+a1.z*c1.z+a1.w*c1.w;
  #pragma unroll
  for (int off=32; off; off>>=1) s += __shfl_down(s, off);
  __shared__ float wsum[4];
  if (lane==0) wsum[wave] = s;
  __syncthreads();
  if (tid==0) lg[b*25+j] = wsum[0]+wsum[1]+wsum[2]+wsum[3] + b2[j];
}

// ---------------- softmax over 25 logits -> kw[b][32] ----------------
__global__ __launch_bounds__(64) void k_smax(const float* lg, float* kw)
{
  int b = threadIdx.x;
  if (b < 8) {
    float mx = -1e30f;
    for (int j=0;j<25;++j) mx = fmaxf(mx, lg[b*25+j]);
    float e[25], s = 0.f;
    for (int j=0;j<25;++j){ e[j]=__expf(lg[b*25+j]-mx); s+=e[j]; }
    float inv = 1.f/s;
    for (int j=0;j<25;++j) kw[b*32+j] = e[j]*inv;
  }
}

// ---------------- generic TN bf16 MFMA GEMM (counted-vmcnt pipeline; KU sub-slices per barrier) ----------------
// OP 0: QKV   flat 768:  b=wg&7, which=wg>>8, xy=(wg>>3)&31   [KU=2: BK=64]
// OP 1: Wo    flat 512:  b=wg&7, xy=wg>>3 (8m x 8n)           [KU=2]
// OP 2: enh   flat 512:  b=wg&7, kg=(wg>>3)>>5, xy=(wg>>3)&31 [KU=2]
// OP 3: gate1 flat 576:  b=wg&7, n=(wg>>3)&7, tap=(wg>>3)>>3  [KU=2]
template<int OP, int BM, int BN, int WAVES_M, int KSTEPS, int KU>
__global__ __launch_bounds__(256)
void k_gemm(KParams p)
{
  constexpr int WAVES_N = 4/WAVES_M;
  constexpr int MT = BM/(WAVES_M*16);
  constexpr int NT = BN/(WAVES_N*16);
  constexpr int ACH = (BM*4 + 255)/256;
  constexpr int BCH = (BN*4 + 255)/256;
  constexpr int WPS = KU*((BM*4)/256 + BCH);   // min per-wave loads per STAGE
  constexpr int NBUF = (KU==2) ? 2 : 3;
  __shared__ bf16 As[NBUF][KU*BM*32];
  __shared__ bf16 Bs[NBUF][KU*BN*32];
  const int tid = threadIdx.x, lane = tid&63, wave = tid>>6;
  const int g = lane>>4, l15 = lane&15;
  const int wm = wave % WAVES_M, wn = wave / WAVES_M;

  int b, which = 0, tapc = 0, kg = 0, m0, n0;
  const bf16 *Aptr, *Bptr;
  long ldb, lda;
  const int wg = blockIdx.x;
  if constexpr (OP==0) {
    b = wg&7; which = wg>>8;
    int xy = (wg>>3)&31;
    m0 = (xy>>3)*BM; n0 = (xy&7)*BN;
    Aptr = (const bf16*)(p.ws+OFF_WBF) + (long)which*262144;
    Bptr = (const bf16*)(p.ws+OFF_CATSEQ) + (long)b*1048576 + (which?512:0);
    ldb = 1024; lda = 512;
  } else if constexpr (OP==1) {
    b = wg&7;
    int xy = wg>>3;
    m0 = (xy>>3)*BM; n0 = (xy&7)*BN;
    Aptr = (const bf16*)(p.ws+OFF_WBF) + 3L*262144;
    Bptr = (const bf16*)(p.ws+OFF_CTX) + (long)b*524288;
    ldb = 512; lda = 512;
  } else if constexpr (OP==2) {
    b = wg&7;
    int loc = wg>>3;
    kg = loc>>5;
    int xy = loc&31;
    m0 = (xy>>3)*BM; n0 = (xy&7)*BN;
    Aptr = (const bf16*)(p.ws+OFF_ENHW);
    Bptr = (const bf16*)(p.ws+OFF_F2) + (long)b*524288;
    ldb = 512; lda = 512;
  } else {
    b = wg&7;
    int loc = wg>>3;
    tapc = loc>>3;
    m0 = 0; n0 = (loc&7)*BN;
    Aptr = (const bf16*)(p.ws+OFF_GW1R) + (long)tapc*32768;
    Bptr = (const bf16*)(p.ws+OFF_CATSEQ) + (long)b*1048576;
    ldb = 1024; lda = 1024;
  }
  const bf16* zp = (const bf16*)(p.ws+OFF_ZP);

  // ---- hoisted per-thread staging state ----
  int tap = (OP==2) ? (kg*72)>>4 : tapc;
  int kcc = (OP==2) ? (kg*72)&15 : 0;
  const bf16* pA[ACH];
  const bf16* pB[BCH];
  bool aact[ACH];
  bool bval[BCH];
  int bpp[BCH], bss8[BCH];
  int dstA[ACH], dstB[BCH];
  #pragma unroll
  for (int i=0;i<ACH;++i) {
    int cc_ = tid + 256*i;
    aact[i] = cc_ < BM*4;
    int c = aact[i] ? cc_ : 0;
    int row = c>>2, slot = c&3, ss = slot ^ ((row>>1)&3);
    dstA[i] = ((c-lane))*8;
    if constexpr (OP==2) pA[i] = Aptr + (long)tap*262144 + (long)(m0+row)*lda + kcc*32 + ss*8;
    else                 pA[i] = Aptr + (long)(m0+row)*lda + ss*8;
  }
  #pragma unroll
  for (int i=0;i<BCH;++i) {
    int c = tid + 256*i;
    int row = c>>2, slot = c&3, ss = slot ^ ((row>>1)&3);
    dstB[i] = ((c-lane))*8;
    bss8[i] = ss*8;
    if constexpr (OP==2 || OP==3) {
      int pp = n0 + row; bpp[i] = pp;
      int hh = (pp>>5) + tap/3 - 1, ww = (pp&31) + tap%3 - 1;
      bool v = ((unsigned)hh < 32u) && ((unsigned)ww < 32u);
      bval[i] = v;
      pB[i] = v ? (Bptr + (long)(hh*32+ww)*ldb + kcc*32 + ss*8) : zp;
    } else {
      bval[i] = true;
      pB[i] = Bptr + (long)(n0+row)*ldb + ss*8;
    }
  }

  auto ADV = [&]() {
    if constexpr (OP==2) {
      ++kcc;
      if (kcc == 16) {
        kcc = 0; ++tap;
        int t3 = tap/3, tm = tap%3;
        #pragma unroll
        for (int i=0;i<ACH;++i) pA[i] += 262144 - 480;
        #pragma unroll
        for (int i=0;i<BCH;++i) {
          int hh = (bpp[i]>>5) + t3 - 1, ww = (bpp[i]&31) + tm - 1;
          bool v = ((unsigned)hh < 32u) && ((unsigned)ww < 32u);
          bval[i] = v;
          pB[i] = v ? (Bptr + (long)(hh*32+ww)*ldb + bss8[i]) : zp;
        }
      } else {
        #pragma unroll
        for (int i=0;i<ACH;++i) pA[i] += 32;
        #pragma unroll
        for (int i=0;i<BCH;++i) pB[i] += bval[i] ? 32 : 0;
      }
    } else if constexpr (OP==3) {
      #pragma unroll
      for (int i=0;i<ACH;++i) pA[i] += 32;
      #pragma unroll
      for (int i=0;i<BCH;++i) pB[i] += bval[i] ? 32 : 0;
    } else {
      #pragma unroll
      for (int i=0;i<ACH;++i) pA[i] += 32;
      #pragma unroll
      for (int i=0;i<BCH;++i) pB[i] += 32;
    }
  };

  auto STAGE = [&](int buf) {
    #pragma unroll
    for (int u=0;u<KU;++u) {
      #pragma unroll
      for (int i=0;i<ACH;++i) if (aact[i]) gload16(pA[i], As[buf] + u*BM*32 + dstA[i]);
      #pragma unroll
      for (int i=0;i<BCH;++i) gload16(pB[i], Bs[buf] + u*BN*32 + dstB[i]);
      ADV();
    }
  };

  f32x4 acc[MT][NT] = {};

  auto COMPUTE = [&](int cur) {
    #pragma unroll
    for (int u=0;u<KU;++u) {
      bf16x8 af[MT], bq_[NT];
      #pragma unroll
      for (int mt=0; mt<MT; ++mt) {
        int row = wm*MT*16 + mt*16 + l15;
        af[mt] = *(const bf16x8*)&As[cur][u*BM*32 + row*32 + 8*(g ^ ((row>>1)&3))];
      }
      #pragma unroll
      for (int nt=0; nt<NT; ++nt) {
        int row = wn*NT*16 + nt*16 + l15;
        bq_[nt] = *(const bf16x8*)&Bs[cur][u*BN*32 + row*32 + 8*(g ^ ((row>>1)&3))];
      }
      __builtin_amdgcn_s_setprio(1);
      #pragma unroll
      for (int mt=0; mt<MT; ++mt)
        #pragma unroll
        for (int nt=0; nt<NT; ++nt)
          acc[mt][nt] = __builtin_amdgcn_mfma_f32_16x16x32_bf16(af[mt], bq_[nt], acc[mt][nt], 0,0,0);
      __builtin_amdgcn_s_setprio(0);
    }
  };

  if constexpr (KU==2) {
    STAGE(0);
    int cur = 0;
    for (int ks = 0; ks < KSTEPS; ++ks) {
      if (ks+1 < KSTEPS) { STAGE(cur^1); waitvm<WPS>(); }
      else               { waitvm<0>(); }
      __builtin_amdgcn_s_barrier();
      __builtin_amdgcn_sched_barrier(0);
      COMPUTE(cur);
      __builtin_amdgcn_s_barrier();
      cur ^= 1;
    }
  } else {
    STAGE(0);
    STAGE(1);
    int cur = 0, stg = 2;
    for (int ks = 0; ks < KSTEPS; ++ks) {
      if (ks+2 < KSTEPS)      { STAGE(stg); stg = (stg==2)?0:stg+1; waitvm<2*WPS>(); }
      else if (ks+1 < KSTEPS) { waitvm<WPS>(); }
      else                    { waitvm<0>(); }
      __builtin_amdgcn_s_barrier();
      __builtin_amdgcn_sched_barrier(0);
      COMPUTE(cur);
      __builtin_amdgcn_s_barrier();
      cur = (cur==2)?0:cur+1;
    }
  }

  #pragma unroll
  for (int mt=0; mt<MT; ++mt) {
    #pragma unroll
    for (int nt=0; nt<NT; ++nt) {
      int mb = m0 + wm*MT*16 + mt*16 + 4*g;
      int n = n0 + wn*NT*16 + nt*16 + l15;
      if constexpr (OP==0) {
        const float* bias = which==0?p.bq: which==1?p.bk:p.bv;
        float v4[4];
        #pragma unroll
        for (int reg=0; reg<4; ++reg) {
          float v = acc[mt][nt][reg] + bias[mb+reg];
          if (which==0) v *= 0.18033688011112042f;   // 0.125 * log2(e)
          v4[reg] = v;
        }
        int h = mb>>6, d0 = mb&63;
        if (which==2) {
          #pragma unroll
          for (int reg=0; reg<4; ++reg)
            ((bf16*)(p.ws+OFF_VT))[((long)(b*8+h)*64 + d0+reg)*1024 + n] = (bf16)v4[reg];
        } else {
          bf16* dst = (bf16*)(p.ws + (which==0?OFF_Q:OFF_K));
          bf16x4 o = {(bf16)v4[0],(bf16)v4[1],(bf16)v4[2],(bf16)v4[3]};
          *(bf16x4*)(dst + ((long)(b*8+h)*1024 + n)*64 + d0) = o;
        }
      } else {
        #pragma unroll
        for (int reg=0; reg<4; ++reg) {
          int m = mb + reg;
          float v = acc[mt][nt][reg];
          if constexpr (OP==1) {
            v += p.bo[m];
            ((bf16*)(p.ws+OFF_FF))[((long)(b*512+m))*1024 + n] = (bf16)v;
          } else if constexpr (OP==2) {
            float* part = (float*)(p.ws+OFF_Q) + (long)kg*4194304;
            part[((long)b*512+m)*1024 + n] = v;
          } else {
            ((float*)(p.ws+OFF_G1P))[((long)((tapc*8+b)*32+m))*1024 + n] = v;
          }
        }
      }
    }
  }
}

// ---------------- enh split-K(2) reduce + BN + SiLU -> out ----------------
__global__ __launch_bounds__(256) void k_enhred(KParams p)
{
  long e = ((long)blockIdx.x*256 + threadIdx.x)*4;
  const float* part = (const float*)(p.ws+OFF_Q);
  float4 a = *(const float4*)(part + e);
  float4 c = *(const float4*)(part + 4194304 + e);
  int m = (int)((e>>10)&511);
  const float* chs = (const float*)(p.ws+OFF_CHS);
  float sc = chs[m], sh = chs[512+m];
  float4 o;
  float y0 = (a.x+c.x)*sc+sh, y1 = (a.y+c.y)*sc+sh, y2 = (a.z+c.z)*sc+sh, y3 = (a.w+c.w)*sc+sh;
  o.x = y0/(1.f+__expf(-y0)); o.y = y1/(1.f+__expf(-y1));
  o.z = y2/(1.f+__expf(-y2)); o.w = y3/(1.f+__expf(-y3));
  *(float4*)(p.out + e) = o;
}

// ---------------- flash attention (KVBLK=64, counted-vmcnt pipeline, no-max softmax, exp2) ----------------
__global__ __launch_bounds__(256)
void k_attn(KParams p)
{
  const bf16* Q = (const bf16*)(p.ws+OFF_Q);
  const bf16* K = (const bf16*)(p.ws+OFF_K);
  const bf16* V = (const bf16*)(p.ws+OFF_VT);
  bf16* ctx = (bf16*)(p.ws+OFF_CTX);
  int wg = blockIdx.x;
  int bh = (wg&7)*8 + (wg>>7);
  int qt = (wg>>3)&15;
  int b = bh>>3, h = bh&7;
  int tid = threadIdx.x, lane = tid&63, wave = tid>>6, g = lane>>4, l15 = lane&15;
  __shared__ bf16 Ks[2][64*64];
  __shared__ bf16 Vs[2][64*64];
  __shared__ bf16 Ps[4][16*64];
  const bf16* Qw = Q + ((long)bh*1024 + qt*64 + wave*16)*64;
  bf16x8 qf[2];
  qf[0] = *(const bf16x8*)(Qw + l15*64 + g*8);
  qf[1] = *(const bf16x8*)(Qw + l15*64 + 32 + g*8);
  const bf16* Kb = K + (long)bh*65536;
  const bf16* Vb = V + (long)bh*65536;
  float lrp[4] = {0,0,0,0};
  f32x4 cacc[4] = {};

  const bf16* pK[2]; const bf16* pV[2];
  int dstK[2], dstV[2];
  {
    int c = tid;
    int krow = c>>3, kslot = c&7, kss = kslot ^ (krow&7);
    pK[0] = Kb + (long)krow*64 + kss*8;
    pK[1] = Kb + (long)(krow+32)*64 + (kslot ^ ((krow+32)&7))*8;
    int d = c>>3, ss2 = kslot ^ (d&7);
    pV[0] = Vb + (long)d*1024 + ss2*8;
    pV[1] = Vb + (long)(d+32)*1024 + ss2*8;
    dstK[0] = (tid-lane)*8;       dstK[1] = (tid-lane+256)*8;
    dstV[0] = (tid-lane)*8;       dstV[1] = (tid-lane+256)*8;
  }
  auto STAGE = [&](int buf) {
    gload16(pK[0], Ks[buf] + dstK[0]);
    gload16(pK[1], Ks[buf] + dstK[1]);
    gload16(pV[0], Vs[buf] + dstV[0]);
    gload16(pV[1], Vs[buf] + dstV[1]);
  };
  auto ADV = [&]() {
    pK[0] += 4096; pK[1] += 4096;
    pV[0] += 64;   pV[1] += 64;
  };

  STAGE(0); ADV();
  int cur = 0;
  for (int step = 0; step < 16; ++step) {
    if (step < 15) { STAGE(cur^1); ADV(); waitvm<4>(); }
    else           { waitvm<0>(); }
    __builtin_amdgcn_s_barrier();
    __builtin_amdgcn_sched_barrier(0);
    f32x4 s0 = {}, s1 = {}, s2 = {}, s3 = {};
    __builtin_amdgcn_s_setprio(1);
    {
      int r0 = l15, r1 = 16+l15, r2 = 32+l15, r3 = 48+l15;
      #pragma unroll
      for (int ks2=0; ks2<2; ++ks2) {
        bf16x8 kf0 = *(const bf16x8*)&Ks[cur][r0*64 + 8*((4*ks2+g)^(r0&7))];
        bf16x8 kf1 = *(const bf16x8*)&Ks[cur][r1*64 + 8*((4*ks2+g)^(r1&7))];
        bf16x8 kf2 = *(const bf16x8*)&Ks[cur][r2*64 + 8*((4*ks2+g)^(r2&7))];
        bf16x8 kf3 = *(const bf16x8*)&Ks[cur][r3*64 + 8*((4*ks2+g)^(r3&7))];
        s0 = __builtin_amdgcn_mfma_f32_16x16x32_bf16(qf[ks2], kf0, s0, 0,0,0);
        s1 = __builtin_amdgcn_mfma_f32_16x16x32_bf16(qf[ks2], kf1, s1, 0,0,0);
        s2 = __builtin_amdgcn_mfma_f32_16x16x32_bf16(qf[ks2], kf2, s2, 0,0,0);
        s3 = __builtin_amdgcn_mfma_f32_16x16x32_bf16(qf[ks2], kf3, s3, 0,0,0);
      }
    }
    __builtin_amdgcn_s_setprio(0);
    bf16* Pw = Ps[wave];
    #pragma unroll
    for (int r=0;r<4;++r) {
      float p0 = __builtin_amdgcn_exp2f(s0[r]);
      float p1 = __builtin_amdgcn_exp2f(s1[r]);
      float p2 = __builtin_amdgcn_exp2f(s2[r]);
      float p3 = __builtin_amdgcn_exp2f(s3[r]);
      int q = 4*g + r;
      int xr = 8*(q&7);
      Pw[q*64 + ((     l15) ^ xr)] = (bf16)p0;
      Pw[q*64 + ((16 + l15) ^ xr)] = (bf16)p1;
      Pw[q*64 + ((32 + l15) ^ xr)] = (bf16)p2;
      Pw[q*64 + ((48 + l15) ^ xr)] = (bf16)p3;
      lrp[r] += (p0+p1)+(p2+p3);
    }
    bf16x8 pa0 = *(const bf16x8*)&Pw[l15*64 + 8*((  g)^(l15&7))];
    bf16x8 pa1 = *(const bf16x8*)&Pw[l15*64 + 8*((4+g)^(l15&7))];
    __builtin_amdgcn_s_setprio(1);
    #pragma unroll
    for (int nt=0;nt<4;++nt) {
      int d = nt*16 + l15;
      bf16x8 vf0 = *(const bf16x8*)&Vs[cur][d*64 + 8*((  g)^(d&7))];
      bf16x8 vf1 = *(const bf16x8*)&Vs[cur][d*64 + 8*((4+g)^(d&7))];
      cacc[nt] = __builtin_amdgcn_mfma_f32_16x16x32_bf16(pa0, vf0, cacc[nt], 0,0,0);
      cacc[nt] = __builtin_amdgcn_mfma_f32_16x16x32_bf16(pa1, vf1, cacc[nt], 0,0,0);
    }
    __builtin_amdgcn_s_setprio(0);
    __builtin_amdgcn_s_barrier();
    cur ^= 1;
  }
  float lr[4];
  #pragma unroll
  for (int r=0;r<4;++r) {
    float s = lrp[r];
    s += __shfl_xor(s, 1);
    s += __shfl_xor(s, 2);
    s += __shfl_xor(s, 4);
    s += __shfl_xor(s, 8);
    lr[r] = s;
  }
  #pragma unroll
  for (int nt=0;nt<4;++nt) {
    #pragma unroll
    for (int r=0;r<4;++r) {
      int q = qt*64 + wave*16 + 4*g + r;
      int cc = h*64 + nt*16 + l15;
      ctx[((long)(b*1024+q))*512 + cc] = (bf16)(cacc[nt][r] / lr[r]);
    }
  }
}

// ---------------- gate1 tap-partial reduce + bias + relu ----------------
__global__ __launch_bounds__(256) void k_g1red(KParams p)
{
  long o = (long)blockIdx.x*256 + threadIdx.x;   // [b][m][n], 262144
  const float* part = (const float*)(p.ws+OFF_G1P);
  int m = (int)((o >> 10) & 31);
  float a = p.gb1[m];
  #pragma unroll
  for (int t=0;t<9;++t) a += part[(long)t*262144 + o];
  ((float*)(p.ws+OFF_Y1))[o] = fmaxf(a, 0.f);
}

// ---------------- gate2 + sigmoid + sum -> gsum[b][p] ----------------
__global__ __launch_bounds__(256)
void k_g2(KParams p, const float* gw2, const float* gb2)
{
  __shared__ float st[3*32*32];
  __shared__ float sg[2][32];
  int h = blockIdx.x, b = blockIdx.y;
  const float* y1 = (const float*)(p.ws+OFF_Y1) + (long)b*32768;
  int tid = threadIdx.x;
  for (int c = tid; c < 768; c += 256) {
    int e = c*4;
    int hr = e>>10, hid = (e>>5)&31, w = e&31;
    int hh = h + hr - 1;
    float4 v = {0,0,0,0};
    if ((unsigned)hh < 32u) v = *(const float4*)(y1 + hid*1024 + hh*32 + w);
    *(float4*)&st[e] = v;
  }
  __syncthreads();
  if (tid < 64) {
    int gg = tid>>5, w = tid&31;
    float acc = gb2[gg];
    for (int hid=0; hid<32; ++hid) {
      #pragma unroll
      for (int u=0;u<3;++u) {
        #pragma unroll
        for (int v=0;v<3;++v) {
          int ww = w + v - 1;
          if ((unsigned)ww < 32u)
            acc += st[(u*32+hid)*32 + ww] * gw2[((gg*32+hid)*3+u)*3+v];
        }
      }
    }
    sg[gg][w] = 1.f/(1.f+__expf(-acc));
  }
  __syncthreads();
  if (tid < 32) ((float*)(p.ws+OFF_GSUM))[b*1024 + h*32 + tid] = sg[0][tid]+sg[1][tid];
}

// ---------------- dynamic 5x5 depthwise conv + gated fuse -> fused2[b][p][c] ----------------
__global__ __launch_bounds__(512)
void k_dyn(KParams p)
{
  __shared__ float ffs[16*1024];
  int ct = blockIdx.x;            // 0..31
  int b  = blockIdx.y;            // 0..7
  int c0 = ct*16;
  int t = threadIdx.x;            // 512
  const bf16* ffg = (const bf16*)(p.ws+OFF_FF) + ((long)(b*512 + c0))*1024;
  #pragma unroll
  for (int k2 = 0; k2 < 4; ++k2) {
    int chunk = t + 512*k2;
    int c = chunk >> 7, j = chunk & 127;
    bf16x8 v = *(const bf16x8*)(ffg + (long)c*1024 + j*8);
    float* d = ffs + c*1024 + j*8;
    #pragma unroll
    for (int e=0;e<8;++e) d[e] = (float)v[e];
  }
  const float* kwp = (const float*)(p.ws+OFF_KW) + b*32;
  float kk[25];
  #pragma unroll
  for (int j=0;j<25;++j) kk[j] = kwp[j];
  __syncthreads();
  int w = t & 31;
  int h0 = t >> 5;                // 0..15
  #pragma unroll
  for (int pass=0; pass<2; ++pass) {
    int h = h0 + pass*16;
    int pos = h*32 + w;
    float gsw = ((const float*)(p.ws+OFF_GSUM))[b*1024 + pos];
    const bf16* cs = (const bf16*)(p.ws+OFF_CATSEQ) + ((long)(b*1024) + pos)*1024 + c0;
    bf16x8 vv0 = *(const bf16x8*)cs;
    bf16x8 vv1 = *(const bf16x8*)(cs + 8);
    bf16x8 rr0 = *(const bf16x8*)(cs + 512);
    bf16x8 rr1 = *(const bf16x8*)(cs + 520);
    bf16 outv[16];
    #pragma unroll
    for (int c=0;c<16;++c) {
      float dyn = 0.f;
      #pragma unroll
      for (int u=0;u<5;++u) {
        int hh = h+u-2;
        bool okh = (unsigned)hh < 32u;
        #pragma unroll
        for (int v=0;v<5;++v) {
          int ww = w+v-2;
          bool ok = okh && ((unsigned)ww < 32u);
          float fv = ffs[c*1024 + (hh&31)*32 + (ww&31)];
          dyn += (ok ? fv : 0.f) * kk[u*5+v];
        }
      }
      float resid = (c < 8) ? ((float)vv0[c] + (float)rr0[c])
                            : ((float)vv1[c-8] + (float)rr1[c-8]);
      float val = gsw*dyn + resid;
      outv[c] = (bf16)val;
    }
    bf16* f2 = (bf16*)(p.ws+OFF_F2) + ((long)(b*1024 + pos))*512 + c0;
    *(bf16x8*)f2       = *(bf16x8*)&outv[0];
    *((bf16x8*)f2 + 1) = *(bf16x8*)&outv[8];
  }
}

extern "C" void kernel_launch(void* const* d_in, const int* in_sizes, int n_in,
                              void* d_out, int out_size, void* d_ws, size_t ws_size,
                              hipStream_t stream)
{
  char* ws = (char*)d_ws;
  KParams p;
  p.vi = (const float*)d_in[0];  p.ir = (const float*)d_in[1];
  p.bq = (const float*)d_in[7];  p.bk = (const float*)d_in[9];
  p.bv = (const float*)d_in[11]; p.bo = (const float*)d_in[13];
  p.gb1 = (const float*)d_in[15];
  p.ws = ws; p.out = (float*)d_out;

  k_prep<<<6692,256,0,stream>>>(p.vi, p.ir,
      (const float*)d_in[6],(const float*)d_in[8],(const float*)d_in[10],(const float*)d_in[12],
      (const float*)d_in[18],(const float*)d_in[14],
      (const float*)d_in[19],(const float*)d_in[20],(const float*)d_in[21],(const float*)d_in[22],(const float*)d_in[23],
      (bf16*)(ws+OFF_WBF),(bf16*)(ws+OFF_ENHW),(bf16*)(ws+OFF_GW1R),(float*)(ws+OFF_CHS),(float*)(ws+OFF_ZP),
      (bf16*)(ws+OFF_CATSEQ),(float*)(ws+OFF_Y1));
  k_mlp1<<<128,256,0,stream>>>((const float*)(ws+OFF_Y1),(const float*)d_in[2],(const float*)d_in[3],(float*)(ws+OFF_HID));
  k_mlp2a<<<200,256,0,stream>>>((const float*)(ws+OFF_HID),(const float*)d_in[4],(const float*)d_in[5],(float*)(ws+OFF_G1P));
  k_smax<<<1,64,0,stream>>>((const float*)(ws+OFF_G1P),(float*)(ws+OFF_KW));
  k_gemm<0,128,128,2,8,2><<<768,256,0,stream>>>(p);
  k_attn<<<1024,256,0,stream>>>(p);
  k_gemm<1,64,128,2,8,2><<<512,256,0,stream>>>(p);
  k_gemm<3,32,128,1,16,2><<<576,256,0,stream>>>(p);
  k_g1red<<<1024,256,0,stream>>>(p);
  k_g2<<<dim3(32,8),256,0,stream>>>(p,(const float*)d_in[16],(const float*)d_in[17]);
  k_dyn<<<dim3(32,8),512,0,stream>>>(p);
  k_gemm<2,128,128,2,36,2><<<512,256,0,stream>>>(p);
  k_enhred<<<4096,256,0,stream>>>(p);
}

// Round 20
// 218.748 us; speedup vs baseline: 1.4770x; 1.0068x over previous
//
#include <hip/hip_runtime.h>

typedef __bf16 bf16;
typedef __attribute__((ext_vector_type(2))) __bf16 bf16x2;
typedef __attribute__((ext_vector_type(4))) __bf16 bf16x4;
typedef __attribute__((ext_vector_type(8))) __bf16 bf16x8;
typedef __attribute__((ext_vector_type(4))) float f32x4;

// ---------------- workspace layout (bytes) ----------------
constexpr size_t OFF_CATSEQ = 0;          // 16777216  [b][p][c(0:512 vi,512:1024 ir)] bf16
constexpr size_t OFF_WBF    = 16777216;   // 2097152   Wq,Wk,Wv,Wo bf16 [co][c]
constexpr size_t OFF_ENHW   = 18874368;   // 4718592   enh_w repacked [t][co][ci] bf16
constexpr size_t OFF_GW1R   = 23592960;   // 589824    gate_w1 repacked [t][hid][ci] bf16
constexpr size_t OFF_CHS    = 24182784;   // 4096      bn scale[512], shift[512]
constexpr size_t OFF_ZP     = 24186880;   // 256       zero page
constexpr size_t OFF_POOL   = 24187136;   // 16384     (unused)
constexpr size_t OFF_HID    = 24203520;   // 65536
constexpr size_t OFF_KW     = 24269056;   // 1024      unnormalized exp(logits) [b][32]
constexpr size_t OFF_Q      = 24270080;   // 8388608  [b][h][p][d] bf16 (x0.125*log2e); later: enh partials (2x16.78MB f32)
constexpr size_t OFF_K      = 32658688;   // 8388608  [b][h][p][d] bf16
constexpr size_t OFF_VT     = 41047296;   // 8388608  [b][h][d][p] bf16; reused as enh partial kg=1
constexpr size_t OFF_CTX    = 49435904;   // 8388608  [b][p][c] bf16
constexpr size_t OFF_FF     = 57824512;   // 8388608  fused_feat [b][c][p] bf16
constexpr size_t OFF_G1P    = 66213120;   // 9437184  gate1 partials [t][b][32][1024] f32
constexpr size_t OFF_Y1     = 75650304;   // 1048576  y1 [b][32][1024] f32 (early: pool partials [b*8+pt][1024])
constexpr size_t OFF_GSUM   = 76698880;   // 32768    [b][p] f32
constexpr size_t OFF_F2     = 76731648;   // 8388608  fused2 [b][p][c] bf16
// total 85120256 bytes

struct KParams {
  const float *vi, *ir, *bq, *bk, *bv, *bo, *gb1;
  char* ws;
  float* out;
};

__device__ __forceinline__ void gload16(const void* g, void* l) {
  __builtin_amdgcn_global_load_lds(
      (const __attribute__((address_space(1))) unsigned int*)g,
      (__attribute__((address_space(3))) unsigned int*)l, 16, 0, 0);
}

template<int N> __device__ __forceinline__ void waitvm() {
  if constexpr (N==0) asm volatile("s_waitcnt vmcnt(0)" ::: "memory");
  else if constexpr (N==1) asm volatile("s_waitcnt vmcnt(1)" ::: "memory");
  else if constexpr (N==2) asm volatile("s_waitcnt vmcnt(2)" ::: "memory");
  else if constexpr (N==3) asm volatile("s_waitcnt vmcnt(3)" ::: "memory");
  else if constexpr (N==4) asm volatile("s_waitcnt vmcnt(4)" ::: "memory");
  else if constexpr (N==6) asm volatile("s_waitcnt vmcnt(6)" ::: "memory");
  else if constexpr (N==8) asm volatile("s_waitcnt vmcnt(8)" ::: "memory");
  else asm volatile("s_waitcnt vmcnt(12)" ::: "memory");
}

// ---------------- merged prep: QKVO cast, bn-fold, zero page, enh/gw1 repack, cat+pool ----------------
// blocks [0,4100): scalar range; [4100,4612): enh repack; [4612,4644): gw1 repack; [4644,6692): cat
__global__ __launch_bounds__(256) void k_prep(const float* vi, const float* ir,
                        const float* Wq, const float* Wk, const float* Wv, const float* Wo,
                        const float* enh_w, const float* gw1,
                        const float* enh_b, const float* gamma, const float* beta,
                        const float* mean, const float* var,
                        bf16* wbf, bf16* enhw, bf16* gw1r, float* chs, float* zp,
                        bf16* cat, float* pool)
{
  __shared__ float ld[9216];
  int blk = blockIdx.x, tid = threadIdx.x;
  if (blk < 4100) {
    long i = (long)blk*256 + tid;
    if (i < 1048576) {
      int which = (int)(i >> 18); long r = i & 262143;
      const float* s = which==0?Wq: which==1?Wk: which==2?Wv:Wo;
      wbf[i] = (bf16)s[r];
    } else if (i < 1048576+512) {
      int c = (int)(i - 1048576);
      float sc = gamma[c]*rsqrtf(var[c]+1e-5f);
      chs[c] = sc; chs[512+c] = (enh_b[c]-mean[c])*sc + beta[c];
    } else if (i < 1048576+512+64) {
      zp[i - (1048576+512)] = 0.f;
    }
  } else if (blk < 4100+512) {
    int co = blk - 4100;
    const float* src = enh_w + (long)co*4608;     // [ci][3][3] contiguous
    #pragma unroll
    for (int it=0; it<18; ++it) ld[tid + 256*it] = src[tid + 256*it];
    __syncthreads();
    #pragma unroll
    for (int t=0;t<9;++t) {
      int ci = tid*2;
      bf16x2 v = { (bf16)ld[ci*9 + t], (bf16)ld[(ci+1)*9 + t] };
      ((bf16x2*)(enhw + (long)t*262144 + (long)co*512))[tid] = v;
    }
  } else if (blk < 4100+512+32) {
    int hid = blk - (4100+512);
    const float* src = gw1 + (long)hid*9216;      // [ci=1024][3][3]
    #pragma unroll
    for (int it=0; it<36; ++it) ld[tid + 256*it] = src[tid + 256*it];
    __syncthreads();
    #pragma unroll
    for (int t=0;t<9;++t) {
      int ci = tid*4;
      bf16x4 v = { (bf16)ld[ci*9+t], (bf16)ld[(ci+1)*9+t],
                   (bf16)ld[(ci+2)*9+t], (bf16)ld[(ci+3)*9+t] };
      *(bf16x4*)(gw1r + (long)t*32768 + (long)hid*1024 + ci) = v;
    }
  } else {
    int idx = blk - (4100+512+32);
    int pt = idx&7, ct = (idx>>3)&31, b = idx>>8;
    const float* src = (ct < 16) ? vi : ir;
    int c0 = (ct & 15) * 32;
    int p0 = pt * 128;
    for (int it = 0; it < 4; ++it) {
      int row = it*8 + (tid>>5);
      int pc  = (tid & 31) * 4;
      float4 v = *(const float4*)(src + ((long)(b*512 + c0 + row))*1024 + p0 + pc);
      ld[row*129+pc+0]=v.x; ld[row*129+pc+1]=v.y; ld[row*129+pc+2]=v.z; ld[row*129+pc+3]=v.w;
    }
    __syncthreads();
    int p = tid >> 1, half = tid & 1;
    bf16x8 o0, o1;
    #pragma unroll
    for (int j = 0; j < 8; ++j) o0[j] = (bf16)ld[(half*16 + j)*129 + p];
    #pragma unroll
    for (int j = 0; j < 8; ++j) o1[j] = (bf16)ld[(half*16 + 8 + j)*129 + p];
    long ccol = (ct<16 ? 0 : 512) + c0 + half*16;
    bf16* dst = cat + ((long)(b*1024 + p0 + p))*1024 + ccol;
    *(bf16x8*)dst       = o0;
    *((bf16x8*)dst + 1) = o1;
    // fused pool partial
    {
      int c = tid>>3, j = tid&7;
      float s = 0.f;
      #pragma unroll
      for (int i=0;i<16;++i) s += ld[c*129 + j*16+i];
      s += __shfl_down(s, 4);
      s += __shfl_down(s, 2);
      s += __shfl_down(s, 1);
      if (j==0) {
        int pc_ = (ct<16 ? 0 : 512) + c0 + c;
        pool[((long)(b*8+pt))*1024 + pc_] = s;
      }
    }
  }
}

// ---------------- mlp1: wave-per-row, partial-sum staging (partials [b*8+pt][1024], vi+ir halves) ----------------
__global__ __launch_bounds__(256) void k_mlp1(const float* partial, const float* w1, const float* b1, float* hid)
{
  __shared__ float pl[8*512];
  int tid = threadIdx.x;
  const float4* pp4 = (const float4*)partial;   // [b*8+pt][256 float4]
  #pragma unroll
  for (int k=0;k<4;++k) {
    int j = tid + 256*k;          // b*128 + c4
    int b = j>>7, c4 = j&127;
    float4 s = {0,0,0,0};
    #pragma unroll
    for (int pt=0;pt<8;++pt) {
      float4 v = pp4[(b*8+pt)*256 + c4];
      float4 w = pp4[(b*8+pt)*256 + 128 + c4];
      s.x+=v.x+w.x; s.y+=v.y+w.y; s.z+=v.z+w.z; s.w+=v.w+w.w;
    }
    float4 o = {s.x*(1.f/1024.f), s.y*(1.f/1024.f), s.z*(1.f/1024.f), s.w*(1.f/1024.f)};
    ((float4*)pl)[j] = o;
  }
  __syncthreads();
  int lane = tid&63, wave = tid>>6;
  #pragma unroll
  for (int rr=0; rr<4; ++rr) {
    int row = (blockIdx.x*4 + wave)*4 + rr;
    const float* wr = w1 + (long)row*512;
    float acc[8] = {};
    #pragma unroll
    for (int e=0;e<8;++e) {
      int c = lane + 64*e;
      float w = wr[c];
      #pragma unroll
      for (int b=0;b<8;++b) acc[b] += w * pl[b*512+c];
    }
    #pragma unroll
    for (int b=0;b<8;++b) {
      float s = acc[b];
      #pragma unroll
      for (int off=32; off; off>>=1) s += __shfl_down(s, off);
      if (lane==0) hid[b*2048 + row] = fmaxf(s + b1[row], 0.f);
    }
  }
}

// ---------------- mlp2a: one block per (b,j) -> unnormalized exp(logit) (no-max safe: |lg|<<1) ----------------
__global__ __launch_bounds__(256) void k_mlp2a(const float* hid, const float* w2, const float* b2, float* ekw)
{
  int blk = blockIdx.x; int b = blk/25, j = blk%25;
  int tid = threadIdx.x, lane = tid&63, wave = tid>>6;
  const float4* h4 = (const float4*)(hid + b*2048);
  const float4* w4 = (const float4*)(w2 + (long)j*2048);
  float4 a0 = h4[tid*2], a1 = h4[tid*2+1];
  float4 c0 = w4[tid*2], c1 = w4[tid*2+1];
  float s = a0.x*c0.x+a0.y*c0.y+a0.z*c0.z+a0.w*c0.w
          + a1.x*c1.x+a1.y*c1.y+a1.z*c1.z+a1.w*c1.w;
  #pragma unroll
  for (int off=32; off; off>>=1) s += __shfl_down(s, off);
  __shared__ float wsum[4];
  if (lane==0) wsum[wave] = s;
  __syncthreads();
  if (tid==0) ekw[b*32+j] = __expf(wsum[0]+wsum[1]+wsum[2]+wsum[3] + b2[j]);
}

// ---------------- generic TN bf16 MFMA GEMM (counted-vmcnt pipeline; KU sub-slices per barrier) ----------------
// OP 0: QKV   flat 768:  b=wg&7, which=wg>>8, xy=(wg>>3)&31   [KU=2: BK=64]
// OP 1: Wo    flat 512:  b=wg&7, xy=wg>>3 (8m x 8n)           [KU=2]
// OP 2: enh   flat 512:  b=wg&7, kg=(wg>>3)>>5, xy=(wg>>3)&31 [KU=2]
// OP 3: gate1 flat 576:  b=wg&7, n=(wg>>3)&7, tap=(wg>>3)>>3  [KU=2]
template<int OP, int BM, int BN, int WAVES_M, int KSTEPS, int KU>
__global__ __launch_bounds__(256)
void k_gemm(KParams p)
{
  constexpr int WAVES_N = 4/WAVES_M;
  constexpr int MT = BM/(WAVES_M*16);
  constexpr int NT = BN/(WAVES_N*16);
  constexpr int ACH = (BM*4 + 255)/256;
  constexpr int BCH = (BN*4 + 255)/256;
  constexpr int WPS = KU*((BM*4)/256 + BCH);   // min per-wave loads per STAGE
  constexpr int NBUF = (KU==2) ? 2 : 3;
  __shared__ bf16 As[NBUF][KU*BM*32];
  __shared__ bf16 Bs[NBUF][KU*BN*32];
  const int tid = threadIdx.x, lane = tid&63, wave = tid>>6;
  const int g = lane>>4, l15 = lane&15;
  const int wm = wave % WAVES_M, wn = wave / WAVES_M;

  int b, which = 0, tapc = 0, kg = 0, m0, n0;
  const bf16 *Aptr, *Bptr;
  long ldb, lda;
  const int wg = blockIdx.x;
  if constexpr (OP==0) {
    b = wg&7; which = wg>>8;
    int xy = (wg>>3)&31;
    m0 = (xy>>3)*BM; n0 = (xy&7)*BN;
    Aptr = (const bf16*)(p.ws+OFF_WBF) + (long)which*262144;
    Bptr = (const bf16*)(p.ws+OFF_CATSEQ) + (long)b*1048576 + (which?512:0);
    ldb = 1024; lda = 512;
  } else if constexpr (OP==1) {
    b = wg&7;
    int xy = wg>>3;
    m0 = (xy>>3)*BM; n0 = (xy&7)*BN;
    Aptr = (const bf16*)(p.ws+OFF_WBF) + 3L*262144;
    Bptr = (const bf16*)(p.ws+OFF_CTX) + (long)b*524288;
    ldb = 512; lda = 512;
  } else if constexpr (OP==2) {
    b = wg&7;
    int loc = wg>>3;
    kg = loc>>5;
    int xy = loc&31;
    m0 = (xy>>3)*BM; n0 = (xy&7)*BN;
    Aptr = (const bf16*)(p.ws+OFF_ENHW);
    Bptr = (const bf16*)(p.ws+OFF_F2) + (long)b*524288;
    ldb = 512; lda = 512;
  } else {
    b = wg&7;
    int loc = wg>>3;
    tapc = loc>>3;
    m0 = 0; n0 = (loc&7)*BN;
    Aptr = (const bf16*)(p.ws+OFF_GW1R) + (long)tapc*32768;
    Bptr = (const bf16*)(p.ws+OFF_CATSEQ) + (long)b*1048576;
    ldb = 1024; lda = 1024;
  }
  const bf16* zp = (const bf16*)(p.ws+OFF_ZP);

  // ---- hoisted per-thread staging state ----
  int tap = (OP==2) ? (kg*72)>>4 : tapc;
  int kcc = (OP==2) ? (kg*72)&15 : 0;
  const bf16* pA[ACH];
  const bf16* pB[BCH];
  bool aact[ACH];
  bool bval[BCH];
  int bpp[BCH], bss8[BCH];
  int dstA[ACH], dstB[BCH];
  #pragma unroll
  for (int i=0;i<ACH;++i) {
    int cc_ = tid + 256*i;
    aact[i] = cc_ < BM*4;
    int c = aact[i] ? cc_ : 0;
    int row = c>>2, slot = c&3, ss = slot ^ ((row>>1)&3);
    dstA[i] = ((c-lane))*8;
    if constexpr (OP==2) pA[i] = Aptr + (long)tap*262144 + (long)(m0+row)*lda + kcc*32 + ss*8;
    else                 pA[i] = Aptr + (long)(m0+row)*lda + ss*8;
  }
  #pragma unroll
  for (int i=0;i<BCH;++i) {
    int c = tid + 256*i;
    int row = c>>2, slot = c&3, ss = slot ^ ((row>>1)&3);
    dstB[i] = ((c-lane))*8;
    bss8[i] = ss*8;
    if constexpr (OP==2 || OP==3) {
      int pp = n0 + row; bpp[i] = pp;
      int hh = (pp>>5) + tap/3 - 1, ww = (pp&31) + tap%3 - 1;
      bool v = ((unsigned)hh < 32u) && ((unsigned)ww < 32u);
      bval[i] = v;
      pB[i] = v ? (Bptr + (long)(hh*32+ww)*ldb + kcc*32 + ss*8) : zp;
    } else {
      bval[i] = true;
      pB[i] = Bptr + (long)(n0+row)*ldb + ss*8;
    }
  }

  auto ADV = [&]() {
    if constexpr (OP==2) {
      ++kcc;
      if (kcc == 16) {
        kcc = 0; ++tap;
        int t3 = tap/3, tm = tap%3;
        #pragma unroll
        for (int i=0;i<ACH;++i) pA[i] += 262144 - 480;
        #pragma unroll
        for (int i=0;i<BCH;++i) {
          int hh = (bpp[i]>>5) + t3 - 1, ww = (bpp[i]&31) + tm - 1;
          bool v = ((unsigned)hh < 32u) && ((unsigned)ww < 32u);
          bval[i] = v;
          pB[i] = v ? (Bptr + (long)(hh*32+ww)*ldb + bss8[i]) : zp;
        }
      } else {
        #pragma unroll
        for (int i=0;i<ACH;++i) pA[i] += 32;
        #pragma unroll
        for (int i=0;i<BCH;++i) pB[i] += bval[i] ? 32 : 0;
      }
    } else if constexpr (OP==3) {
      #pragma unroll
      for (int i=0;i<ACH;++i) pA[i] += 32;
      #pragma unroll
      for (int i=0;i<BCH;++i) pB[i] += bval[i] ? 32 : 0;
    } else {
      #pragma unroll
      for (int i=0;i<ACH;++i) pA[i] += 32;
      #pragma unroll
      for (int i=0;i<BCH;++i) pB[i] += 32;
    }
  };

  auto STAGE = [&](int buf) {
    #pragma unroll
    for (int u=0;u<KU;++u) {
      #pragma unroll
      for (int i=0;i<ACH;++i) if (aact[i]) gload16(pA[i], As[buf] + u*BM*32 + dstA[i]);
      #pragma unroll
      for (int i=0;i<BCH;++i) gload16(pB[i], Bs[buf] + u*BN*32 + dstB[i]);
      ADV();
    }
  };

  f32x4 acc[MT][NT] = {};

  auto COMPUTE = [&](int cur) {
    #pragma unroll
    for (int u=0;u<KU;++u) {
      bf16x8 af[MT], bq_[NT];
      #pragma unroll
      for (int mt=0; mt<MT; ++mt) {
        int row = wm*MT*16 + mt*16 + l15;
        af[mt] = *(const bf16x8*)&As[cur][u*BM*32 + row*32 + 8*(g ^ ((row>>1)&3))];
      }
      #pragma unroll
      for (int nt=0; nt<NT; ++nt) {
        int row = wn*NT*16 + nt*16 + l15;
        bq_[nt] = *(const bf16x8*)&Bs[cur][u*BN*32 + row*32 + 8*(g ^ ((row>>1)&3))];
      }
      __builtin_amdgcn_s_setprio(1);
      #pragma unroll
      for (int mt=0; mt<MT; ++mt)
        #pragma unroll
        for (int nt=0; nt<NT; ++nt)
          acc[mt][nt] = __builtin_amdgcn_mfma_f32_16x16x32_bf16(af[mt], bq_[nt], acc[mt][nt], 0,0,0);
      __builtin_amdgcn_s_setprio(0);
    }
  };

  if constexpr (KU==2) {
    STAGE(0);
    int cur = 0;
    for (int ks = 0; ks < KSTEPS; ++ks) {
      if (ks+1 < KSTEPS) { STAGE(cur^1); waitvm<WPS>(); }
      else               { waitvm<0>(); }
      __builtin_amdgcn_s_barrier();
      __builtin_amdgcn_sched_barrier(0);
      COMPUTE(cur);
      __builtin_amdgcn_s_barrier();
      cur ^= 1;
    }
  } else {
    STAGE(0);
    STAGE(1);
    int cur = 0, stg = 2;
    for (int ks = 0; ks < KSTEPS; ++ks) {
      if (ks+2 < KSTEPS)      { STAGE(stg); stg = (stg==2)?0:stg+1; waitvm<2*WPS>(); }
      else if (ks+1 < KSTEPS) { waitvm<WPS>(); }
      else                    { waitvm<0>(); }
      __builtin_amdgcn_s_barrier();
      __builtin_amdgcn_sched_barrier(0);
      COMPUTE(cur);
      __builtin_amdgcn_s_barrier();
      cur = (cur==2)?0:cur+1;
    }
  }

  #pragma unroll
  for (int mt=0; mt<MT; ++mt) {
    #pragma unroll
    for (int nt=0; nt<NT; ++nt) {
      int mb = m0 + wm*MT*16 + mt*16 + 4*g;
      int n = n0 + wn*NT*16 + nt*16 + l15;
      if constexpr (OP==0) {
        const float* bias = which==0?p.bq: which==1?p.bk:p.bv;
        float v4[4];
        #pragma unroll
        for (int reg=0; reg<4; ++reg) {
          float v = acc[mt][nt][reg] + bias[mb+reg];
          if (which==0) v *= 0.18033688011112042f;   // 0.125 * log2(e)
          v4[reg] = v;
        }
        int h = mb>>6, d0 = mb&63;
        if (which==2) {
          #pragma unroll
          for (int reg=0; reg<4; ++reg)
            ((bf16*)(p.ws+OFF_VT))[((long)(b*8+h)*64 + d0+reg)*1024 + n] = (bf16)v4[reg];
        } else {
          bf16* dst = (bf16*)(p.ws + (which==0?OFF_Q:OFF_K));
          bf16x4 o = {(bf16)v4[0],(bf16)v4[1],(bf16)v4[2],(bf16)v4[3]};
          *(bf16x4*)(dst + ((long)(b*8+h)*1024 + n)*64 + d0) = o;
        }
      } else {
        #pragma unroll
        for (int reg=0; reg<4; ++reg) {
          int m = mb + reg;
          float v = acc[mt][nt][reg];
          if constexpr (OP==1) {
            v += p.bo[m];
            ((bf16*)(p.ws+OFF_FF))[((long)(b*512+m))*1024 + n] = (bf16)v;
          } else if constexpr (OP==2) {
            float* part = (float*)(p.ws+OFF_Q) + (long)kg*4194304;
            part[((long)b*512+m)*1024 + n] = v;
          } else {
            ((float*)(p.ws+OFF_G1P))[((long)((tapc*8+b)*32+m))*1024 + n] = v;
          }
        }
      }
    }
  }
}

// ---------------- enh split-K(2) reduce + BN + SiLU -> out ----------------
__global__ __launch_bounds__(256) void k_enhred(KParams p)
{
  long e = ((long)blockIdx.x*256 + threadIdx.x)*4;
  const float* part = (const float*)(p.ws+OFF_Q);
  float4 a = *(const float4*)(part + e);
  float4 c = *(const float4*)(part + 4194304 + e);
  int m = (int)((e>>10)&511);
  const float* chs = (const float*)(p.ws+OFF_CHS);
  float sc = chs[m], sh = chs[512+m];
  float4 o;
  float y0 = (a.x+c.x)*sc+sh, y1 = (a.y+c.y)*sc+sh, y2 = (a.z+c.z)*sc+sh, y3 = (a.w+c.w)*sc+sh;
  o.x = y0/(1.f+__expf(-y0)); o.y = y1/(1.f+__expf(-y1));
  o.z = y2/(1.f+__expf(-y2)); o.w = y3/(1.f+__expf(-y3));
  *(float4*)(p.out + e) = o;
}

// ---------------- flash attention (KVBLK=64, counted-vmcnt pipeline, no-max softmax, exp2) ----------------
__global__ __launch_bounds__(256)
void k_attn(KParams p)
{
  const bf16* Q = (const bf16*)(p.ws+OFF_Q);
  const bf16* K = (const bf16*)(p.ws+OFF_K);
  const bf16* V = (const bf16*)(p.ws+OFF_VT);
  bf16* ctx = (bf16*)(p.ws+OFF_CTX);
  int wg = blockIdx.x;
  int bh = (wg&7)*8 + (wg>>7);
  int qt = (wg>>3)&15;
  int b = bh>>3, h = bh&7;
  int tid = threadIdx.x, lane = tid&63, wave = tid>>6, g = lane>>4, l15 = lane&15;
  __shared__ bf16 Ks[2][64*64];
  __shared__ bf16 Vs[2][64*64];
  __shared__ bf16 Ps[4][16*64];
  const bf16* Qw = Q + ((long)bh*1024 + qt*64 + wave*16)*64;
  bf16x8 qf[2];
  qf[0] = *(const bf16x8*)(Qw + l15*64 + g*8);
  qf[1] = *(const bf16x8*)(Qw + l15*64 + 32 + g*8);
  const bf16* Kb = K + (long)bh*65536;
  const bf16* Vb = V + (long)bh*65536;
  float lrp[4] = {0,0,0,0};
  f32x4 cacc[4] = {};

  const bf16* pK[2]; const bf16* pV[2];
  int dstK[2], dstV[2];
  {
    int c = tid;
    int krow = c>>3, kslot = c&7, kss = kslot ^ (krow&7);
    pK[0] = Kb + (long)krow*64 + kss*8;
    pK[1] = Kb + (long)(krow+32)*64 + (kslot ^ ((krow+32)&7))*8;
    int d = c>>3, ss2 = kslot ^ (d&7);
    pV[0] = Vb + (long)d*1024 + ss2*8;
    pV[1] = Vb + (long)(d+32)*1024 + ss2*8;
    dstK[0] = (tid-lane)*8;       dstK[1] = (tid-lane+256)*8;
    dstV[0] = (tid-lane)*8;       dstV[1] = (tid-lane+256)*8;
  }
  auto STAGE = [&](int buf) {
    gload16(pK[0], Ks[buf] + dstK[0]);
    gload16(pK[1], Ks[buf] + dstK[1]);
    gload16(pV[0], Vs[buf] + dstV[0]);
    gload16(pV[1], Vs[buf] + dstV[1]);
  };
  auto ADV = [&]() {
    pK[0] += 4096; pK[1] += 4096;
    pV[0] += 64;   pV[1] += 64;
  };

  STAGE(0); ADV();
  int cur = 0;
  for (int step = 0; step < 16; ++step) {
    if (step < 15) { STAGE(cur^1); ADV(); waitvm<4>(); }
    else           { waitvm<0>(); }
    __builtin_amdgcn_s_barrier();
    __builtin_amdgcn_sched_barrier(0);
    f32x4 s0 = {}, s1 = {}, s2 = {}, s3 = {};
    __builtin_amdgcn_s_setprio(1);
    {
      int r0 = l15, r1 = 16+l15, r2 = 32+l15, r3 = 48+l15;
      #pragma unroll
      for (int ks2=0; ks2<2; ++ks2) {
        bf16x8 kf0 = *(const bf16x8*)&Ks[cur][r0*64 + 8*((4*ks2+g)^(r0&7))];
        bf16x8 kf1 = *(const bf16x8*)&Ks[cur][r1*64 + 8*((4*ks2+g)^(r1&7))];
        bf16x8 kf2 = *(const bf16x8*)&Ks[cur][r2*64 + 8*((4*ks2+g)^(r2&7))];
        bf16x8 kf3 = *(const bf16x8*)&Ks[cur][r3*64 + 8*((4*ks2+g)^(r3&7))];
        s0 = __builtin_amdgcn_mfma_f32_16x16x32_bf16(qf[ks2], kf0, s0, 0,0,0);
        s1 = __builtin_amdgcn_mfma_f32_16x16x32_bf16(qf[ks2], kf1, s1, 0,0,0);
        s2 = __builtin_amdgcn_mfma_f32_16x16x32_bf16(qf[ks2], kf2, s2, 0,0,0);
        s3 = __builtin_amdgcn_mfma_f32_16x16x32_bf16(qf[ks2], kf3, s3, 0,0,0);
      }
    }
    __builtin_amdgcn_s_setprio(0);
    bf16* Pw = Ps[wave];
    #pragma unroll
    for (int r=0;r<4;++r) {
      float p0 = __builtin_amdgcn_exp2f(s0[r]);
      float p1 = __builtin_amdgcn_exp2f(s1[r]);
      float p2 = __builtin_amdgcn_exp2f(s2[r]);
      float p3 = __builtin_amdgcn_exp2f(s3[r]);
      int q = 4*g + r;
      int xr = 8*(q&7);
      Pw[q*64 + ((     l15) ^ xr)] = (bf16)p0;
      Pw[q*64 + ((16 + l15) ^ xr)] = (bf16)p1;
      Pw[q*64 + ((32 + l15) ^ xr)] = (bf16)p2;
      Pw[q*64 + ((48 + l15) ^ xr)] = (bf16)p3;
      lrp[r] += (p0+p1)+(p2+p3);
    }
    bf16x8 pa0 = *(const bf16x8*)&Pw[l15*64 + 8*((  g)^(l15&7))];
    bf16x8 pa1 = *(const bf16x8*)&Pw[l15*64 + 8*((4+g)^(l15&7))];
    __builtin_amdgcn_s_setprio(1);
    #pragma unroll
    for (int nt=0;nt<4;++nt) {
      int d = nt*16 + l15;
      bf16x8 vf0 = *(const bf16x8*)&Vs[cur][d*64 + 8*((  g)^(d&7))];
      bf16x8 vf1 = *(const bf16x8*)&Vs[cur][d*64 + 8*((4+g)^(d&7))];
      cacc[nt] = __builtin_amdgcn_mfma_f32_16x16x32_bf16(pa0, vf0, cacc[nt], 0,0,0);
      cacc[nt] = __builtin_amdgcn_mfma_f32_16x16x32_bf16(pa1, vf1, cacc[nt], 0,0,0);
    }
    __builtin_amdgcn_s_setprio(0);
    __builtin_amdgcn_s_barrier();
    cur ^= 1;
  }
  float lr[4];
  #pragma unroll
  for (int r=0;r<4;++r) {
    float s = lrp[r];
    s += __shfl_xor(s, 1);
    s += __shfl_xor(s, 2);
    s += __shfl_xor(s, 4);
    s += __shfl_xor(s, 8);
    lr[r] = s;
  }
  #pragma unroll
  for (int nt=0;nt<4;++nt) {
    #pragma unroll
    for (int r=0;r<4;++r) {
      int q = qt*64 + wave*16 + 4*g + r;
      int cc = h*64 + nt*16 + l15;
      ctx[((long)(b*1024+q))*512 + cc] = (bf16)(cacc[nt][r] / lr[r]);
    }
  }
}

// ---------------- gate1 tap-partial reduce + bias + relu ----------------
__global__ __launch_bounds__(256) void k_g1red(KParams p)
{
  long o = (long)blockIdx.x*256 + threadIdx.x;   // [b][m][n], 262144
  const float* part = (const float*)(p.ws+OFF_G1P);
  int m = (int)((o >> 10) & 31);
  float a = p.gb1[m];
  #pragma unroll
  for (int t=0;t<9;++t) a += part[(long)t*262144 + o];
  ((float*)(p.ws+OFF_Y1))[o] = fmaxf(a, 0.f);
}

// ---------------- gate2 + sigmoid + sum -> gsum[b][p] ----------------
__global__ __launch_bounds__(256)
void k_g2(KParams p, const float* gw2, const float* gb2)
{
  __shared__ float st[3*32*32];
  __shared__ float sg[2][32];
  int h = blockIdx.x, b = blockIdx.y;
  const float* y1 = (const float*)(p.ws+OFF_Y1) + (long)b*32768;
  int tid = threadIdx.x;
  for (int c = tid; c < 768; c += 256) {
    int e = c*4;
    int hr = e>>10, hid = (e>>5)&31, w = e&31;
    int hh = h + hr - 1;
    float4 v = {0,0,0,0};
    if ((unsigned)hh < 32u) v = *(const float4*)(y1 + hid*1024 + hh*32 + w);
    *(float4*)&st[e] = v;
  }
  __syncthreads();
  if (tid < 64) {
    int gg = tid>>5, w = tid&31;
    float acc = gb2[gg];
    for (int hid=0; hid<32; ++hid) {
      #pragma unroll
      for (int u=0;u<3;++u) {
        #pragma unroll
        for (int v=0;v<3;++v) {
          int ww = w + v - 1;
          if ((unsigned)ww < 32u)
            acc += st[(u*32+hid)*32 + ww] * gw2[((gg*32+hid)*3+u)*3+v];
        }
      }
    }
    sg[gg][w] = 1.f/(1.f+__expf(-acc));
  }
  __syncthreads();
  if (tid < 32) ((float*)(p.ws+OFF_GSUM))[b*1024 + h*32 + tid] = sg[0][tid]+sg[1][tid];
}

// ---------------- dynamic 5x5 depthwise conv + gated fuse -> fused2[b][p][c] ----------------
__global__ __launch_bounds__(512)
void k_dyn(KParams p)
{
  __shared__ float ffs[16*1024];
  int ct = blockIdx.x;            // 0..31
  int b  = blockIdx.y;            // 0..7
  int c0 = ct*16;
  int t = threadIdx.x;            // 512
  const bf16* ffg = (const bf16*)(p.ws+OFF_FF) + ((long)(b*512 + c0))*1024;
  #pragma unroll
  for (int k2 = 0; k2 < 4; ++k2) {
    int chunk = t + 512*k2;
    int c = chunk >> 7, j = chunk & 127;
    bf16x8 v = *(const bf16x8*)(ffg + (long)c*1024 + j*8);
    float* d = ffs + c*1024 + j*8;
    #pragma unroll
    for (int e=0;e<8;++e) d[e] = (float)v[e];
  }
  // normalize kernel weights locally (ekw = unnormalized exp(logits))
  const float* ekw = (const float*)(p.ws+OFF_KW) + b*32;
  float kk[25];
  {
    float ssum = 0.f;
    #pragma unroll
    for (int j=0;j<25;++j) { kk[j] = ekw[j]; ssum += kk[j]; }
    float inv = 1.f/ssum;
    #pragma unroll
    for (int j=0;j<25;++j) kk[j] *= inv;
  }
  __syncthreads();
  int w = t & 31;
  int h0 = t >> 5;                // 0..15
  #pragma unroll
  for (int pass=0; pass<2; ++pass) {
    int h = h0 + pass*16;
    int pos = h*32 + w;
    float gsw = ((const float*)(p.ws+OFF_GSUM))[b*1024 + pos];
    const bf16* cs = (const bf16*)(p.ws+OFF_CATSEQ) + ((long)(b*1024) + pos)*1024 + c0;
    bf16x8 vv0 = *(const bf16x8*)cs;
    bf16x8 vv1 = *(const bf16x8*)(cs + 8);
    bf16x8 rr0 = *(const bf16x8*)(cs + 512);
    bf16x8 rr1 = *(const bf16x8*)(cs + 520);
    bf16 outv[16];
    #pragma unroll
    for (int c=0;c<16;++c) {
      float dyn = 0.f;
      #pragma unroll
      for (int u=0;u<5;++u) {
        int hh = h+u-2;
        bool okh = (unsigned)hh < 32u;
        #pragma unroll
        for (int v=0;v<5;++v) {
          int ww = w+v-2;
          bool ok = okh && ((unsigned)ww < 32u);
          float fv = ffs[c*1024 + (hh&31)*32 + (ww&31)];
          dyn += (ok ? fv : 0.f) * kk[u*5+v];
        }
      }
      float resid = (c < 8) ? ((float)vv0[c] + (float)rr0[c])
                            : ((float)vv1[c-8] + (float)rr1[c-8]);
      float val = gsw*dyn + resid;
      outv[c] = (bf16)val;
    }
    bf16* f2 = (bf16*)(p.ws+OFF_F2) + ((long)(b*1024 + pos))*512 + c0;
    *(bf16x8*)f2       = *(bf16x8*)&outv[0];
    *((bf16x8*)f2 + 1) = *(bf16x8*)&outv[8];
  }
}

extern "C" void kernel_launch(void* const* d_in, const int* in_sizes, int n_in,
                              void* d_out, int out_size, void* d_ws, size_t ws_size,
                              hipStream_t stream)
{
  char* ws = (char*)d_ws;
  KParams p;
  p.vi = (const float*)d_in[0];  p.ir = (const float*)d_in[1];
  p.bq = (const float*)d_in[7];  p.bk = (const float*)d_in[9];
  p.bv = (const float*)d_in[11]; p.bo = (const float*)d_in[13];
  p.gb1 = (const float*)d_in[15];
  p.ws = ws; p.out = (float*)d_out;

  k_prep<<<6692,256,0,stream>>>(p.vi, p.ir,
      (const float*)d_in[6],(const float*)d_in[8],(const float*)d_in[10],(const float*)d_in[12],
      (const float*)d_in[18],(const float*)d_in[14],
      (const float*)d_in[19],(const float*)d_in[20],(const float*)d_in[21],(const float*)d_in[22],(const float*)d_in[23],
      (bf16*)(ws+OFF_WBF),(bf16*)(ws+OFF_ENHW),(bf16*)(ws+OFF_GW1R),(float*)(ws+OFF_CHS),(float*)(ws+OFF_ZP),
      (bf16*)(ws+OFF_CATSEQ),(float*)(ws+OFF_Y1));
  k_mlp1<<<128,256,0,stream>>>((const float*)(ws+OFF_Y1),(const float*)d_in[2],(const float*)d_in[3],(float*)(ws+OFF_HID));
  k_mlp2a<<<200,256,0,stream>>>((const float*)(ws+OFF_HID),(const float*)d_in[4],(const float*)d_in[5],(float*)(ws+OFF_KW));
  k_gemm<0,128,128,2,8,2><<<768,256,0,stream>>>(p);
  k_attn<<<1024,256,0,stream>>>(p);
  k_gemm<1,64,128,2,8,2><<<512,256,0,stream>>>(p);
  k_gemm<3,32,128,1,16,2><<<576,256,0,stream>>>(p);
  k_g1red<<<1024,256,0,stream>>>(p);
  k_g2<<<dim3(32,8),256,0,stream>>>(p,(const float*)d_in[16],(const float*)d_in[17]);
  k_dyn<<<dim3(32,8),512,0,stream>>>(p);
  k_gemm<2,128,128,2,36,2><<<512,256,0,stream>>>(p);
  k_enhred<<<4096,256,0,stream>>>(p);
}